// Round 1
// baseline (1205.177 us; speedup 1.0000x reference)
//
#include <hip/hip_runtime.h>

static constexpr int NN  = 100000;   // nodes
static constexpr int NE  = 1600000;  // edges per set
static constexpr int DIM = 64;
static constexpr int HH  = 32;       // H2

// ---------------- CSR build ----------------

__global__ void k_count(const int* __restrict__ pe, const int* __restrict__ ne,
                        int* __restrict__ dp, int* __restrict__ dn) {
  int t = blockIdx.x * 256 + threadIdx.x;
  if (t < NE) {
    int dst = pe[NE + t];
    atomicAdd(&dp[dst], 1);
  } else if (t < 2 * NE) {
    int e = t - NE;
    int dst = ne[NE + e];
    atomicAdd(&dn[dst], 1);
  }
}

// One block per edge set: exclusive prefix sum of deg -> rowptr (length NN).
__global__ void k_scan(const int* __restrict__ dp, const int* __restrict__ dn,
                       int* __restrict__ rp, int* __restrict__ rn) {
  const int* deg = (blockIdx.x == 0) ? dp : dn;
  int* row       = (blockIdx.x == 0) ? rp : rn;
  const int T  = 1024;
  const int CH = (NN + T - 1) / T;  // 98
  int t  = threadIdx.x;
  int lo = t * CH;
  int hi = min(lo + CH, NN);
  int s = 0;
  for (int i = lo; i < hi; ++i) s += deg[i];
  __shared__ int sm[T];
  sm[t] = s;
  __syncthreads();
  for (int off = 1; off < T; off <<= 1) {
    int v = (t >= off) ? sm[t - off] : 0;
    __syncthreads();
    sm[t] += v;
    __syncthreads();
  }
  int run = (t == 0) ? 0 : sm[t - 1];
  for (int i = lo; i < hi; ++i) { row[i] = run; run += deg[i]; }
}

// Fill: slot = old value of rowptr[dst]; afterwards rowptr[i] == end offset of node i.
__global__ void k_fill(const int* __restrict__ pe, const int* __restrict__ ne,
                       int* __restrict__ rp, int* __restrict__ rn,
                       int* __restrict__ cp, int* __restrict__ cn) {
  int t = blockIdx.x * 256 + threadIdx.x;
  if (t < NE) {
    int src = pe[t];
    int dst = pe[NE + t];
    int slot = atomicAdd(&rp[dst], 1);
    cp[slot] = src;
  } else if (t < 2 * NE) {
    int e = t - NE;
    int src = ne[e];
    int dst = ne[NE + e];
    int slot = atomicAdd(&rn[dst], 1);
    cn[slot] = src;
  }
}

// ---------------- mean aggregation (pull), wave64 per node, lane = feature ----------------
// After k_fill, row[i] = end offset; start = (i==0) ? 0 : row[i-1].
__global__ void k_aggr(const float* __restrict__ feat,
                       const int* __restrict__ rp, const int* __restrict__ cp,
                       const int* __restrict__ rn, const int* __restrict__ cn,
                       float* __restrict__ aggP, float* __restrict__ aggN) {
  int gid  = blockIdx.x * 256 + threadIdx.x;
  int node = gid >> 6;
  int lane = threadIdx.x & 63;
  if (node >= NN) return;

  int sP = node ? rp[node - 1] : 0;
  int eP = rp[node];
  float a = 0.f;
  for (int e = sP; e < eP; ++e) a += feat[cp[e] * DIM + lane];
  aggP[node * DIM + lane] = a / (float)max(eP - sP, 1);

  int sN = node ? rn[node - 1] : 0;
  int eN = rn[node];
  float b = 0.f;
  for (int e = sN; e < eN; ++e) b += feat[cn[e] * DIM + lane];
  aggN[node * DIM + lane] = b / (float)max(eN - sN, 1);
}

// ---------------- layer-1 dense: z[:, h*32:(h+1)*32] = relu(agg_h @ wl + x @ wr + b) ----------------
__global__ void k_dense1(const float* __restrict__ x,
                         const float* __restrict__ aggP, const float* __restrict__ aggN,
                         const float* __restrict__ w_pl, const float* __restrict__ w_pr,
                         const float* __restrict__ b_p,
                         const float* __restrict__ w_nl, const float* __restrict__ w_nr,
                         const float* __restrict__ b_n,
                         float* z) {
  const int h = blockIdx.y;
  const float* wl   = h ? w_nl : w_pl;   // [64][32]
  const float* wr   = h ? w_nr : w_pr;   // [64][32]
  const float* bias = h ? b_n  : b_p;
  const float* agg  = h ? aggN : aggP;

  __shared__ float s_wl[DIM][HH];
  __shared__ float s_wr[DIM][HH];
  for (int i = threadIdx.x; i < DIM * HH; i += 256) {
    s_wl[i >> 5][i & 31] = wl[i];
    s_wr[i >> 5][i & 31] = wr[i];
  }
  __syncthreads();

  int node = blockIdx.x * 256 + threadIdx.x;
  if (node >= NN) return;

  float acc[HH];
#pragma unroll
  for (int j = 0; j < HH; ++j) acc[j] = bias[j];

  const float4* arow = (const float4*)(agg + node * DIM);
  const float4* xrow = (const float4*)(x   + node * DIM);
#pragma unroll 2
  for (int k4 = 0; k4 < DIM / 4; ++k4) {
    float4 a  = arow[k4];
    float4 xv = xrow[k4];
#pragma unroll
    for (int u = 0; u < 4; ++u) {
      int k = k4 * 4 + u;
      float av  = (&a.x)[u];
      float xvv = (&xv.x)[u];
#pragma unroll
      for (int j = 0; j < HH; ++j)
        acc[j] += av * s_wl[k][j] + xvv * s_wr[k][j];
    }
  }

  float4* zr = (float4*)(z + node * DIM + h * HH);
#pragma unroll
  for (int j4 = 0; j4 < HH / 4; ++j4) {
    float4 v;
    v.x = fmaxf(acc[j4 * 4 + 0], 0.f);
    v.y = fmaxf(acc[j4 * 4 + 1], 0.f);
    v.z = fmaxf(acc[j4 * 4 + 2], 0.f);
    v.w = fmaxf(acc[j4 * 4 + 3], 0.f);
    zr[j4] = v;
  }
}

// ---------------- layer-2 dense ----------------
// h=0: out_pos = [aggP[0:32], aggN[32:64]] @ w2_pl + z[:,0:32] @ w2_pr + b2_p
// h=1: out_neg = [aggP[32:64], aggN[0:32]] @ w2_nl + z[:,32:64] @ w2_nr + b2_n
// NOTE: z and out may alias (each thread reads only the 128B it later writes).
__global__ void k_dense2(const float* z,
                         const float* __restrict__ aggP, const float* __restrict__ aggN,
                         const float* __restrict__ w2_pl, const float* __restrict__ w2_pr,
                         const float* __restrict__ b2_p,
                         const float* __restrict__ w2_nl, const float* __restrict__ w2_nr,
                         const float* __restrict__ b2_n,
                         float* out) {
  const int h = blockIdx.y;
  const float* wl   = h ? w2_nl : w2_pl;  // [64][32]
  const float* wr   = h ? w2_nr : w2_pr;  // [32][32]
  const float* bias = h ? b2_n  : b2_p;

  __shared__ float s_wl[DIM][HH];
  __shared__ float s_wr[HH][HH];
  for (int i = threadIdx.x; i < DIM * HH; i += 256) s_wl[i >> 5][i & 31] = wl[i];
  for (int i = threadIdx.x; i < HH * HH; i += 256)  s_wr[i >> 5][i & 31] = wr[i];
  __syncthreads();

  int node = blockIdx.x * 256 + threadIdx.x;
  if (node >= NN) return;

  float acc[HH];
#pragma unroll
  for (int j = 0; j < HH; ++j) acc[j] = bias[j];

  // cat stream part 1 (k = 0..31)
  const float4* c0 = (const float4*)(aggP + node * DIM + (h ? HH : 0));
  // cat stream part 2 (k = 32..63)
  const float4* c1 = (const float4*)(aggN + node * DIM + (h ? 0 : HH));
  const float4* zh = (const float4*)(z    + node * DIM + h * HH);

#pragma unroll 2
  for (int k4 = 0; k4 < HH / 4; ++k4) {
    float4 v = c0[k4];
#pragma unroll
    for (int u = 0; u < 4; ++u) {
      int k = k4 * 4 + u;
      float vv = (&v.x)[u];
#pragma unroll
      for (int j = 0; j < HH; ++j) acc[j] += vv * s_wl[k][j];
    }
  }
#pragma unroll 2
  for (int k4 = 0; k4 < HH / 4; ++k4) {
    float4 v = c1[k4];
#pragma unroll
    for (int u = 0; u < 4; ++u) {
      int k = 32 + k4 * 4 + u;
      float vv = (&v.x)[u];
#pragma unroll
      for (int j = 0; j < HH; ++j) acc[j] += vv * s_wl[k][j];
    }
  }
#pragma unroll 2
  for (int k4 = 0; k4 < HH / 4; ++k4) {
    float4 v = zh[k4];
#pragma unroll
    for (int u = 0; u < 4; ++u) {
      int k = k4 * 4 + u;
      float vv = (&v.x)[u];
#pragma unroll
      for (int j = 0; j < HH; ++j) acc[j] += vv * s_wr[k][j];
    }
  }

  float4* orow = (float4*)(out + node * DIM + h * HH);
#pragma unroll
  for (int j4 = 0; j4 < HH / 4; ++j4) {
    float4 v;
    v.x = fmaxf(acc[j4 * 4 + 0], 0.f);
    v.y = fmaxf(acc[j4 * 4 + 1], 0.f);
    v.z = fmaxf(acc[j4 * 4 + 2], 0.f);
    v.w = fmaxf(acc[j4 * 4 + 3], 0.f);
    orow[j4] = v;
  }
}

// ---------------- launch ----------------

extern "C" void kernel_launch(void* const* d_in, const int* in_sizes, int n_in,
                              void* d_out, int out_size, void* d_ws, size_t ws_size,
                              hipStream_t stream) {
  const float* x     = (const float*)d_in[0];
  const int*   pe    = (const int*)d_in[1];
  const int*   ne    = (const int*)d_in[2];
  const float* w1_pl = (const float*)d_in[3];
  const float* w1_pr = (const float*)d_in[4];
  const float* b1_p  = (const float*)d_in[5];
  const float* w1_nl = (const float*)d_in[6];
  const float* w1_nr = (const float*)d_in[7];
  const float* b1_n  = (const float*)d_in[8];
  const float* w2_pl = (const float*)d_in[9];
  const float* w2_pr = (const float*)d_in[10];
  const float* b2_p  = (const float*)d_in[11];
  const float* w2_nl = (const float*)d_in[12];
  const float* w2_nr = (const float*)d_in[13];
  const float* b2_n  = (const float*)d_in[14];

  char* ws = (char*)d_ws;
  size_t off = 0;
  auto alloc = [&](size_t bytes) -> void* {
    void* p = ws + off;
    off = (off + bytes + 255) & ~(size_t)255;
    return p;
  };

  int*   deg_p = (int*)alloc((size_t)NN * 4);
  int*   deg_n = (int*)alloc((size_t)NN * 4);
  int*   row_p = (int*)alloc((size_t)NN * 4);
  int*   row_n = (int*)alloc((size_t)NN * 4);
  int*   col_p = (int*)alloc((size_t)NE * 4);
  int*   col_n = (int*)alloc((size_t)NE * 4);
  float* aggA  = (float*)alloc((size_t)NN * DIM * 4);
  float* aggB  = (float*)alloc((size_t)NN * DIM * 4);
  float* z     = (float*)d_out;  // layer-1 output lives in d_out, overwritten by layer 2

  hipMemsetAsync(deg_p, 0, (size_t)NN * 4, stream);
  hipMemsetAsync(deg_n, 0, (size_t)NN * 4, stream);

  const int eb = (2 * NE + 255) / 256;
  k_count<<<eb, 256, 0, stream>>>(pe, ne, deg_p, deg_n);
  k_scan<<<2, 1024, 0, stream>>>(deg_p, deg_n, row_p, row_n);
  k_fill<<<eb, 256, 0, stream>>>(pe, ne, row_p, row_n, col_p, col_n);

  const int ab = (NN * 64) / 256;  // wave per node
  k_aggr<<<ab, 256, 0, stream>>>(x, row_p, col_p, row_n, col_n, aggA, aggB);

  dim3 dgrid((NN + 255) / 256, 2);
  k_dense1<<<dgrid, 256, 0, stream>>>(x, aggA, aggB,
                                      w1_pl, w1_pr, b1_p, w1_nl, w1_nr, b1_n, z);

  k_aggr<<<ab, 256, 0, stream>>>(z, row_p, col_p, row_n, col_n, aggA, aggB);

  k_dense2<<<dgrid, 256, 0, stream>>>(z, aggA, aggB,
                                      w2_pl, w2_pr, b2_p, w2_nl, w2_nr, b2_n,
                                      (float*)d_out);
}

// Round 3
// 707.379 us; speedup vs baseline: 1.7037x; 1.7037x over previous
//
#include <hip/hip_runtime.h>
#include <hip/hip_fp16.h>

using uint = unsigned int;

static constexpr int NN  = 100000;   // nodes
static constexpr int NE  = 1600000;  // edges per set
static constexpr int DIM = 64;
static constexpr int HH  = 32;

__device__ __forceinline__ float2 up16(uint v) {
  __half2 h = *reinterpret_cast<__half2*>(&v);
  return __half22float2(h);
}
__device__ __forceinline__ uint pk16(float a, float b) {
  __half2 h = __floats2half2_rn(a, b);
  return *reinterpret_cast<uint*>(&h);
}

// ---------------- CSR build (single atomic pass) ----------------

// rank[e] = arrival order of edge e within its dst; deg[dst] counted as side effect.
__global__ void k_rank(const int* __restrict__ pe, const int* __restrict__ ne,
                       int* __restrict__ dp, int* __restrict__ dn,
                       int* __restrict__ rkp, int* __restrict__ rkn) {
  int t = blockIdx.x * 256 + threadIdx.x;
  if (t < NE) {
    rkp[t] = atomicAdd(&dp[pe[NE + t]], 1);
  } else if (t < 2 * NE) {
    int e = t - NE;
    rkn[e] = atomicAdd(&dn[ne[NE + e]], 1);
  }
}

// Exclusive prefix sum of deg -> row[0..NN], row[NN] = NE.
__global__ void k_scan(const int* __restrict__ dp, const int* __restrict__ dn,
                       int* __restrict__ rp, int* __restrict__ rn) {
  const int* deg = (blockIdx.x == 0) ? dp : dn;
  int* row       = (blockIdx.x == 0) ? rp : rn;
  const int T  = 1024;
  const int CH = (NN + T - 1) / T;
  int t  = threadIdx.x;
  int lo = t * CH;
  int hi = min(lo + CH, NN);
  int s = 0;
  for (int i = lo; i < hi; ++i) s += deg[i];
  __shared__ int sm[T];
  sm[t] = s;
  __syncthreads();
  for (int off = 1; off < T; off <<= 1) {
    int v = (t >= off) ? sm[t - off] : 0;
    __syncthreads();
    sm[t] += v;
    __syncthreads();
  }
  int run = (t == 0) ? 0 : sm[t - 1];
  for (int i = lo; i < hi; ++i) { row[i] = run; run += deg[i]; }
  if (t == T - 1) row[NN] = NE;
}

// col[row[dst] + rank[e]] = src  (atomic-free; row stays exclusive & reusable)
__global__ void k_fill(const int* __restrict__ pe, const int* __restrict__ ne,
                       const int* __restrict__ rp, const int* __restrict__ rn,
                       const int* __restrict__ rkp, const int* __restrict__ rkn,
                       int* __restrict__ cp, int* __restrict__ cn) {
  int t = blockIdx.x * 256 + threadIdx.x;
  if (t < NE) {
    int src = pe[t];
    int dst = pe[NE + t];
    cp[rp[dst] + rkp[t]] = src;
  } else if (t < 2 * NE) {
    int e = t - NE;
    int src = ne[e];
    int dst = ne[NE + e];
    cn[rn[dst] + rkn[e]] = src;
  }
}

// ---------------- pre-transform layer 1 ----------------
// h = blockIdx.y: 0 -> pos half, 1 -> neg half.
// y1[:, h*32:(h+1)*32] = x @ wl   (f16)
// r1[:, h*32:(h+1)*32] = x @ wr + b   (f32)   [r1 lives in d_out]
__global__ void k_pre1(const float* __restrict__ x,
                       const float* __restrict__ w1_pl, const float* __restrict__ w1_pr,
                       const float* __restrict__ b1_p,
                       const float* __restrict__ w1_nl, const float* __restrict__ w1_nr,
                       const float* __restrict__ b1_n,
                       uint* __restrict__ y1u, float* __restrict__ r1) {
  const int h = blockIdx.y;
  const float* wl   = h ? w1_nl : w1_pl;  // [64][32]
  const float* wr   = h ? w1_nr : w1_pr;  // [64][32]
  const float* bias = h ? b1_n  : b1_p;

  __shared__ float s_wl[DIM][HH];
  __shared__ float s_wr[DIM][HH];
  for (int i = threadIdx.x; i < DIM * HH; i += 256) {
    s_wl[i >> 5][i & 31] = wl[i];
    s_wr[i >> 5][i & 31] = wr[i];
  }
  __syncthreads();

  int node = blockIdx.x * 256 + threadIdx.x;
  if (node >= NN) return;

  float ay[HH], ar[HH];
#pragma unroll
  for (int j = 0; j < HH; ++j) { ay[j] = 0.f; ar[j] = bias[j]; }

  const float4* xrow = (const float4*)(x + (size_t)node * DIM);
#pragma unroll 4
  for (int k4 = 0; k4 < DIM / 4; ++k4) {
    float4 xv = xrow[k4];
#pragma unroll
    for (int u = 0; u < 4; ++u) {
      int k = k4 * 4 + u;
      float xk = (&xv.x)[u];
#pragma unroll
      for (int j = 0; j < HH; ++j) {
        ay[j] += xk * s_wl[k][j];
        ar[j] += xk * s_wr[k][j];
      }
    }
  }

  uint*  yo = y1u + (size_t)node * 32 + h * 16;
  float* ro = r1  + (size_t)node * 64 + h * 32;
#pragma unroll
  for (int j = 0; j < 16; ++j) yo[j] = pk16(ay[2 * j], ay[2 * j + 1]);
#pragma unroll
  for (int j = 0; j < HH; ++j) ro[j] = ar[j];
}

// ---------------- aggregation 1 (fused layer-1 epilogue) ----------------
// wave per node. Pos edges gather y1[:,0:32] (f16), neg gather y1[:,32:64].
// z = relu([meanP | meanN] + r1)
// NOTE: r1 and z ALIAS (both d_out): each thread reads exactly the 8 bytes of
// r1 it then overwrites — same-thread read-then-write, so no __restrict__ here.
__global__ void k_aggr1(const uint* __restrict__ y1u,
                        const int* __restrict__ rp, const int* __restrict__ cp,
                        const int* __restrict__ rn, const int* __restrict__ cn,
                        const float* r1,
                        float* z) {
  int gid  = blockIdx.x * 256 + threadIdx.x;
  int node = gid >> 6;
  if (node >= NN) return;
  int lane = threadIdx.x & 63;
  int g = lane >> 4;      // edge slot 0..3
  int f = lane & 15;      // feature pair: features 2f, 2f+1

  // pos
  int s = rp[node], e = rp[node + 1];
  float a0 = 0.f, a1 = 0.f;
  for (int i = s + g; i < e; i += 4) {
    int c = cp[i];
    float2 v = up16(y1u[(size_t)c * 32 + f]);
    a0 += v.x; a1 += v.y;
  }
  a0 += __shfl_xor(a0, 16); a0 += __shfl_xor(a0, 32);
  a1 += __shfl_xor(a1, 16); a1 += __shfl_xor(a1, 32);
  float invp = 1.f / (float)max(e - s, 1);

  // neg
  s = rn[node]; e = rn[node + 1];
  float b0 = 0.f, b1 = 0.f;
  for (int i = s + g; i < e; i += 4) {
    int c = cn[i];
    float2 v = up16(y1u[(size_t)c * 32 + 16 + f]);
    b0 += v.x; b1 += v.y;
  }
  b0 += __shfl_xor(b0, 16); b0 += __shfl_xor(b0, 32);
  b1 += __shfl_xor(b1, 16); b1 += __shfl_xor(b1, 32);
  float invn = 1.f / (float)max(e - s, 1);

  size_t base = (size_t)node * 64;
  if (g == 0) {
    float2 o;
    o.x = fmaxf(a0 * invp + r1[base + 2 * f], 0.f);
    o.y = fmaxf(a1 * invp + r1[base + 2 * f + 1], 0.f);
    *(float2*)(z + base + 2 * f) = o;
  } else if (g == 1) {
    float2 o;
    o.x = fmaxf(b0 * invn + r1[base + 32 + 2 * f], 0.f);
    o.y = fmaxf(b1 * invn + r1[base + 32 + 2 * f + 1], 0.f);
    *(float2*)(z + base + 32 + 2 * f) = o;
  }
}

// ---------------- pre-transform layer 2 ----------------
// 6 tasks (blockIdx.y), each: out = z_half @ mat (32x32) [+ bias]
// t0: zp@w2_pl[0:32]  -> u_pos[:, 0:32]  (f16)
// t1: zn@w2_nl[0:32]  -> u_pos[:,32:64]  (f16)
// t2: zn@w2_pl[32:64] -> u_neg[:, 0:32]  (f16)
// t3: zp@w2_nl[32:64] -> u_neg[:,32:64]  (f16)
// t4: zp@w2_pr + b2_p -> r2[:, 0:32]     (f32)
// t5: zn@w2_nr + b2_n -> r2[:,32:64]     (f32)
__global__ void k_mid(const float* __restrict__ z,
                      const float* __restrict__ w2_pl, const float* __restrict__ w2_pr,
                      const float* __restrict__ b2_p,
                      const float* __restrict__ w2_nl, const float* __restrict__ w2_nr,
                      const float* __restrict__ b2_n,
                      uint* __restrict__ u_pos, uint* __restrict__ u_neg,
                      float* __restrict__ r2) {
  const int t = blockIdx.y;
  const float* mat;
  const float* bias = nullptr;
  int srcHalf;            // 0 = zp, 1 = zn
  switch (t) {
    case 0: mat = w2_pl;            srcHalf = 0; break;
    case 1: mat = w2_nl;            srcHalf = 1; break;
    case 2: mat = w2_pl + 32 * 32;  srcHalf = 1; break;
    case 3: mat = w2_nl + 32 * 32;  srcHalf = 0; break;
    case 4: mat = w2_pr; bias = b2_p; srcHalf = 0; break;
    default: mat = w2_nr; bias = b2_n; srcHalf = 1; break;
  }

  __shared__ float s_m[HH][HH];
  for (int i = threadIdx.x; i < HH * HH; i += 256) s_m[i >> 5][i & 31] = mat[i];
  __syncthreads();

  int node = blockIdx.x * 256 + threadIdx.x;
  if (node >= NN) return;

  float acc[HH];
#pragma unroll
  for (int j = 0; j < HH; ++j) acc[j] = bias ? bias[j] : 0.f;

  const float4* zrow = (const float4*)(z + (size_t)node * 64 + srcHalf * 32);
#pragma unroll 4
  for (int k4 = 0; k4 < HH / 4; ++k4) {
    float4 v = zrow[k4];
#pragma unroll
    for (int u = 0; u < 4; ++u) {
      int k = k4 * 4 + u;
      float vv = (&v.x)[u];
#pragma unroll
      for (int j = 0; j < HH; ++j) acc[j] += vv * s_m[k][j];
    }
  }

  if (t < 4) {
    uint* o = (t < 2 ? u_pos : u_neg) + (size_t)node * 32 + (t & 1) * 16;
#pragma unroll
    for (int j = 0; j < 16; ++j) o[j] = pk16(acc[2 * j], acc[2 * j + 1]);
  } else {
    float* o = r2 + (size_t)node * 64 + (t - 4) * 32;
#pragma unroll
    for (int j = 0; j < HH; ++j) o[j] = acc[j];
  }
}

// ---------------- aggregation 2 (fused final epilogue) ----------------
// aggP = pos-mean of u_pos (64 f16), aggN = neg-mean of u_neg.
// out = relu(aggP + aggN + r2)
__global__ void k_aggr2(const uint* __restrict__ u_pos, const uint* __restrict__ u_neg,
                        const int* __restrict__ rp, const int* __restrict__ cp,
                        const int* __restrict__ rn, const int* __restrict__ cn,
                        const float* __restrict__ r2,
                        float* __restrict__ out) {
  int gid  = blockIdx.x * 256 + threadIdx.x;
  int node = gid >> 6;
  if (node >= NN) return;
  int lane = threadIdx.x & 63;
  int g = lane >> 5;      // edge slot 0..1
  int f = lane & 31;      // feature pair: features 2f, 2f+1

  int s = rp[node], e = rp[node + 1];
  float a0 = 0.f, a1 = 0.f;
  for (int i = s + g; i < e; i += 2) {
    int c = cp[i];
    float2 v = up16(u_pos[(size_t)c * 32 + f]);
    a0 += v.x; a1 += v.y;
  }
  a0 += __shfl_xor(a0, 32);
  a1 += __shfl_xor(a1, 32);
  float invp = 1.f / (float)max(e - s, 1);

  s = rn[node]; e = rn[node + 1];
  float b0 = 0.f, b1 = 0.f;
  for (int i = s + g; i < e; i += 2) {
    int c = cn[i];
    float2 v = up16(u_neg[(size_t)c * 32 + f]);
    b0 += v.x; b1 += v.y;
  }
  b0 += __shfl_xor(b0, 32);
  b1 += __shfl_xor(b1, 32);
  float invn = 1.f / (float)max(e - s, 1);

  if (g == 0) {
    size_t base = (size_t)node * 64 + 2 * f;
    float2 o;
    o.x = fmaxf(a0 * invp + b0 * invn + r2[base], 0.f);
    o.y = fmaxf(a1 * invp + b1 * invn + r2[base + 1], 0.f);
    *(float2*)(out + base) = o;
  }
}

// ---------------- launch ----------------

extern "C" void kernel_launch(void* const* d_in, const int* in_sizes, int n_in,
                              void* d_out, int out_size, void* d_ws, size_t ws_size,
                              hipStream_t stream) {
  const float* x     = (const float*)d_in[0];
  const int*   pe    = (const int*)d_in[1];
  const int*   ne    = (const int*)d_in[2];
  const float* w1_pl = (const float*)d_in[3];
  const float* w1_pr = (const float*)d_in[4];
  const float* b1_p  = (const float*)d_in[5];
  const float* w1_nl = (const float*)d_in[6];
  const float* w1_nr = (const float*)d_in[7];
  const float* b1_n  = (const float*)d_in[8];
  const float* w2_pl = (const float*)d_in[9];
  const float* w2_pr = (const float*)d_in[10];
  const float* b2_p  = (const float*)d_in[11];
  const float* w2_nl = (const float*)d_in[12];
  const float* w2_nr = (const float*)d_in[13];
  const float* b2_n  = (const float*)d_in[14];

  char* ws = (char*)d_ws;
  size_t off = 0;
  auto alloc = [&](size_t bytes) -> char* {
    char* p = ws + off;
    off = (off + bytes + 255) & ~(size_t)255;
    return p;
  };

  // deg_p/deg_n CONTIGUOUS in one allocation so a single exact memset covers both
  // (round-2 bug: separate aligned allocs left a gap -> tail of deg_n unzeroed -> fault).
  int* deg   = (int*)alloc((size_t)2 * NN * 4);
  int* deg_p = deg;
  int* deg_n = deg + NN;
  int* row_p = (int*)alloc((size_t)(NN + 1) * 4);
  int* row_n = (int*)alloc((size_t)(NN + 1) * 4);
  int* col_p = (int*)alloc((size_t)NE * 4);
  int* col_n = (int*)alloc((size_t)NE * 4);

  // union region A (25.6MB), lifetimes disjoint in stream order:
  //   rank_p+rank_n (12.8MB, k_rank..k_fill)
  //   y1 (12.8MB, k_pre1..k_aggr1)
  //   u_pos+u_neg (25.6MB, k_mid..k_aggr2)
  char* regA   = alloc((size_t)NN * 64 * 4);
  int*  rank_p = (int*)regA;
  int*  rank_n = (int*)(regA + (size_t)NE * 4);
  uint* y1u    = (uint*)regA;
  uint* u_pos  = (uint*)regA;
  uint* u_neg  = (uint*)(regA + (size_t)NN * 32 * 4);

  float* r2 = (float*)alloc((size_t)NN * 64 * 4);

  // r1 and z both live in d_out (k_aggr1 does same-thread read->write; k_mid
  // then reads z; k_aggr2 fully overwrites d_out with the final output).
  float* r1 = (float*)d_out;
  float* z  = (float*)d_out;

  hipMemsetAsync(deg, 0, (size_t)2 * NN * 4, stream);

  const int eb = (2 * NE + 255) / 256;
  const int nb = (NN + 255) / 256;
  const int ab = (NN * 64 + 255) / 256;

  k_rank<<<eb, 256, 0, stream>>>(pe, ne, deg_p, deg_n, rank_p, rank_n);
  k_scan<<<2, 1024, 0, stream>>>(deg_p, deg_n, row_p, row_n);
  k_fill<<<eb, 256, 0, stream>>>(pe, ne, row_p, row_n, rank_p, rank_n, col_p, col_n);

  dim3 g1(nb, 2);
  k_pre1<<<g1, 256, 0, stream>>>(x, w1_pl, w1_pr, b1_p, w1_nl, w1_nr, b1_n, y1u, r1);

  k_aggr1<<<ab, 256, 0, stream>>>(y1u, row_p, col_p, row_n, col_n, r1, z);

  dim3 g2(nb, 6);
  k_mid<<<g2, 256, 0, stream>>>(z, w2_pl, w2_pr, b2_p, w2_nl, w2_nr, b2_n,
                                u_pos, u_neg, r2);

  k_aggr2<<<ab, 256, 0, stream>>>(u_pos, u_neg, row_p, col_p, row_n, col_n, r2,
                                  (float*)d_out);
}

// Round 4
// 544.185 us; speedup vs baseline: 2.2146x; 1.2999x over previous
//
#include <hip/hip_runtime.h>
#include <hip/hip_fp16.h>

using uint = unsigned int;

static constexpr int NN  = 100000;   // nodes
static constexpr int NE  = 1600000;  // edges per set
static constexpr int DIM = 64;
static constexpr int HH  = 32;
static constexpr int NBLK = (NN + 255) / 256;  // 391 scan blocks per edge set

__device__ __forceinline__ float2 up16(uint v) {
  __half2 h = *reinterpret_cast<__half2*>(&v);
  return __half22float2(h);
}
__device__ __forceinline__ uint pk16(float a, float b) {
  __half2 h = __floats2half2_rn(a, b);
  return *reinterpret_cast<uint*>(&h);
}

// ---------------- CSR build ----------------

// rank[e] = arrival order of edge e within its dst; deg[dst] counted as side effect.
__global__ void k_rank(const int* __restrict__ pe, const int* __restrict__ ne,
                       int* __restrict__ dp, int* __restrict__ dn,
                       int* __restrict__ rkp, int* __restrict__ rkn) {
  int t = blockIdx.x * 256 + threadIdx.x;
  if (t < NE) {
    rkp[t] = atomicAdd(&dp[pe[NE + t]], 1);
  } else if (t < 2 * NE) {
    int e = t - NE;
    rkn[e] = atomicAdd(&dn[ne[NE + e]], 1);
  }
}

// --- two-level scan: A) per-block sums, B) scan block sums, C) write rowptr ---

__global__ void k_bsum(const int* __restrict__ deg,  // [2*NN], set-major
                       int* __restrict__ bsum) {     // [2*512]
  int set = blockIdx.y;
  int i   = blockIdx.x * 256 + threadIdx.x;
  int v   = (i < NN) ? deg[set * NN + i] : 0;
  __shared__ int sm[256];
  sm[threadIdx.x] = v;
  __syncthreads();
  for (int off = 128; off > 0; off >>= 1) {
    if (threadIdx.x < off) sm[threadIdx.x] += sm[threadIdx.x + off];
    __syncthreads();
  }
  if (threadIdx.x == 0) bsum[set * 512 + blockIdx.x] = sm[0];
}

// One block, 1024 threads: independent exclusive scans of the two 391-entry
// segments (set s in threads [s*512, s*512+391)).
__global__ void k_bscan(const int* __restrict__ bsum, int* __restrict__ bofs) {
  int t   = threadIdx.x;
  int seg = t >> 9;        // 0 or 1
  int idx = t & 511;
  int v = (idx < NBLK) ? bsum[seg * 512 + idx] : 0;
  __shared__ int sm[1024];
  sm[t] = v;
  __syncthreads();
  for (int off = 1; off < 512; off <<= 1) {
    int add = (idx >= off) ? sm[t - off] : 0;
    __syncthreads();
    sm[t] += add;
    __syncthreads();
  }
  if (idx < NBLK) bofs[seg * 512 + idx] = (idx == 0) ? 0 : sm[t - 1];
}

__global__ void k_rowwrite(const int* __restrict__ deg,   // [2*NN]
                           const int* __restrict__ bofs,  // [2*512]
                           int* __restrict__ rp, int* __restrict__ rn) {
  int set = blockIdx.y;
  int* row = set ? rn : rp;
  int i = blockIdx.x * 256 + threadIdx.x;
  int v = (i < NN) ? deg[set * NN + i] : 0;
  __shared__ int sm[256];
  sm[threadIdx.x] = v;
  __syncthreads();
  for (int off = 1; off < 256; off <<= 1) {
    int add = (threadIdx.x >= off) ? sm[threadIdx.x - off] : 0;
    __syncthreads();
    sm[threadIdx.x] += add;
    __syncthreads();
  }
  int excl = (threadIdx.x == 0) ? 0 : sm[threadIdx.x - 1];
  if (i < NN) row[i] = bofs[set * 512 + blockIdx.x] + excl;
  if (blockIdx.x == NBLK - 1 && threadIdx.x == 255) row[NN] = NE;
}

// col[row[dst] + rank[e]] = src  (atomic-free)
__global__ void k_fill(const int* __restrict__ pe, const int* __restrict__ ne,
                       const int* __restrict__ rp, const int* __restrict__ rn,
                       const int* __restrict__ rkp, const int* __restrict__ rkn,
                       int* __restrict__ cp, int* __restrict__ cn) {
  int t = blockIdx.x * 256 + threadIdx.x;
  if (t < NE) {
    int src = pe[t];
    int dst = pe[NE + t];
    cp[rp[dst] + rkp[t]] = src;
  } else if (t < 2 * NE) {
    int e = t - NE;
    int src = ne[e];
    int dst = ne[NE + e];
    cn[rn[dst] + rkn[e]] = src;
  }
}

// ---------------- pre-transform layer 1 ----------------
// y1[:, h*32:(h+1)*32] = x @ wl (f16) ; r1[:, h*32:(h+1)*32] = x @ wr + b (f32, in d_out)
__global__ void k_pre1(const float* __restrict__ x,
                       const float* __restrict__ w1_pl, const float* __restrict__ w1_pr,
                       const float* __restrict__ b1_p,
                       const float* __restrict__ w1_nl, const float* __restrict__ w1_nr,
                       const float* __restrict__ b1_n,
                       uint* __restrict__ y1u, float* __restrict__ r1) {
  const int h = blockIdx.y;
  const float* wl   = h ? w1_nl : w1_pl;  // [64][32]
  const float* wr   = h ? w1_nr : w1_pr;  // [64][32]
  const float* bias = h ? b1_n  : b1_p;

  __shared__ float s_wl[DIM][HH];
  __shared__ float s_wr[DIM][HH];
  for (int i = threadIdx.x; i < DIM * HH; i += 256) {
    s_wl[i >> 5][i & 31] = wl[i];
    s_wr[i >> 5][i & 31] = wr[i];
  }
  __syncthreads();

  int node = blockIdx.x * 256 + threadIdx.x;
  if (node >= NN) return;

  float ay[HH], ar[HH];
#pragma unroll
  for (int j = 0; j < HH; ++j) { ay[j] = 0.f; ar[j] = bias[j]; }

  const float4* xrow = (const float4*)(x + (size_t)node * DIM);
#pragma unroll 4
  for (int k4 = 0; k4 < DIM / 4; ++k4) {
    float4 xv = xrow[k4];
#pragma unroll
    for (int u = 0; u < 4; ++u) {
      int k = k4 * 4 + u;
      float xk = (&xv.x)[u];
#pragma unroll
      for (int j = 0; j < HH; ++j) {
        ay[j] += xk * s_wl[k][j];
        ar[j] += xk * s_wr[k][j];
      }
    }
  }

  uint*  yo = y1u + (size_t)node * 32 + h * 16;
  float* ro = r1  + (size_t)node * 64 + h * 32;
#pragma unroll
  for (int j = 0; j < 16; ++j) yo[j] = pk16(ay[2 * j], ay[2 * j + 1]);
#pragma unroll
  for (int j = 0; j < HH; ++j) ro[j] = ar[j];
}

// ---------------- aggregation 1 (fused layer-1 epilogue) ----------------
// NOTE: r1 and z ALIAS (both d_out): same-thread read-then-write only.
__global__ void k_aggr1(const uint* __restrict__ y1u,
                        const int* __restrict__ rp, const int* __restrict__ cp,
                        const int* __restrict__ rn, const int* __restrict__ cn,
                        const float* r1,
                        float* z) {
  int gid  = blockIdx.x * 256 + threadIdx.x;
  int node = gid >> 6;
  if (node >= NN) return;
  int lane = threadIdx.x & 63;
  int g = lane >> 4;      // edge slot 0..3
  int f = lane & 15;      // feature pair: features 2f, 2f+1

  int s = rp[node], e = rp[node + 1];
  float a0 = 0.f, a1 = 0.f;
  for (int i = s + g; i < e; i += 4) {
    int c = cp[i];
    float2 v = up16(y1u[(size_t)c * 32 + f]);
    a0 += v.x; a1 += v.y;
  }
  a0 += __shfl_xor(a0, 16); a0 += __shfl_xor(a0, 32);
  a1 += __shfl_xor(a1, 16); a1 += __shfl_xor(a1, 32);
  float invp = 1.f / (float)max(e - s, 1);

  s = rn[node]; e = rn[node + 1];
  float b0 = 0.f, b1 = 0.f;
  for (int i = s + g; i < e; i += 4) {
    int c = cn[i];
    float2 v = up16(y1u[(size_t)c * 32 + 16 + f]);
    b0 += v.x; b1 += v.y;
  }
  b0 += __shfl_xor(b0, 16); b0 += __shfl_xor(b0, 32);
  b1 += __shfl_xor(b1, 16); b1 += __shfl_xor(b1, 32);
  float invn = 1.f / (float)max(e - s, 1);

  size_t base = (size_t)node * 64;
  if (g == 0) {
    float2 o;
    o.x = fmaxf(a0 * invp + r1[base + 2 * f], 0.f);
    o.y = fmaxf(a1 * invp + r1[base + 2 * f + 1], 0.f);
    *(float2*)(z + base + 2 * f) = o;
  } else if (g == 1) {
    float2 o;
    o.x = fmaxf(b0 * invn + r1[base + 32 + 2 * f], 0.f);
    o.y = fmaxf(b1 * invn + r1[base + 32 + 2 * f + 1], 0.f);
    *(float2*)(z + base + 32 + 2 * f) = o;
  }
}

// ---------------- pre-transform layer 2 ----------------
__global__ void k_mid(const float* __restrict__ z,
                      const float* __restrict__ w2_pl, const float* __restrict__ w2_pr,
                      const float* __restrict__ b2_p,
                      const float* __restrict__ w2_nl, const float* __restrict__ w2_nr,
                      const float* __restrict__ b2_n,
                      uint* __restrict__ u_pos, uint* __restrict__ u_neg,
                      float* __restrict__ r2) {
  const int t = blockIdx.y;
  const float* mat;
  const float* bias = nullptr;
  int srcHalf;            // 0 = zp, 1 = zn
  switch (t) {
    case 0: mat = w2_pl;            srcHalf = 0; break;
    case 1: mat = w2_nl;            srcHalf = 1; break;
    case 2: mat = w2_pl + 32 * 32;  srcHalf = 1; break;
    case 3: mat = w2_nl + 32 * 32;  srcHalf = 0; break;
    case 4: mat = w2_pr; bias = b2_p; srcHalf = 0; break;
    default: mat = w2_nr; bias = b2_n; srcHalf = 1; break;
  }

  __shared__ float s_m[HH][HH];
  for (int i = threadIdx.x; i < HH * HH; i += 256) s_m[i >> 5][i & 31] = mat[i];
  __syncthreads();

  int node = blockIdx.x * 256 + threadIdx.x;
  if (node >= NN) return;

  float acc[HH];
#pragma unroll
  for (int j = 0; j < HH; ++j) acc[j] = bias ? bias[j] : 0.f;

  const float4* zrow = (const float4*)(z + (size_t)node * 64 + srcHalf * 32);
#pragma unroll 4
  for (int k4 = 0; k4 < HH / 4; ++k4) {
    float4 v = zrow[k4];
#pragma unroll
    for (int u = 0; u < 4; ++u) {
      int k = k4 * 4 + u;
      float vv = (&v.x)[u];
#pragma unroll
      for (int j = 0; j < HH; ++j) acc[j] += vv * s_m[k][j];
    }
  }

  if (t < 4) {
    uint* o = (t < 2 ? u_pos : u_neg) + (size_t)node * 32 + (t & 1) * 16;
#pragma unroll
    for (int j = 0; j < 16; ++j) o[j] = pk16(acc[2 * j], acc[2 * j + 1]);
  } else {
    float* o = r2 + (size_t)node * 64 + (t - 4) * 32;
#pragma unroll
    for (int j = 0; j < HH; ++j) o[j] = acc[j];
  }
}

// ---------------- aggregation 2 (fused final epilogue) ----------------
__global__ void k_aggr2(const uint* __restrict__ u_pos, const uint* __restrict__ u_neg,
                        const int* __restrict__ rp, const int* __restrict__ cp,
                        const int* __restrict__ rn, const int* __restrict__ cn,
                        const float* __restrict__ r2,
                        float* __restrict__ out) {
  int gid  = blockIdx.x * 256 + threadIdx.x;
  int node = gid >> 6;
  if (node >= NN) return;
  int lane = threadIdx.x & 63;
  int g = lane >> 5;      // edge slot 0..1
  int f = lane & 31;      // feature pair

  int s = rp[node], e = rp[node + 1];
  float a0 = 0.f, a1 = 0.f;
  for (int i = s + g; i < e; i += 2) {
    int c = cp[i];
    float2 v = up16(u_pos[(size_t)c * 32 + f]);
    a0 += v.x; a1 += v.y;
  }
  a0 += __shfl_xor(a0, 32);
  a1 += __shfl_xor(a1, 32);
  float invp = 1.f / (float)max(e - s, 1);

  s = rn[node]; e = rn[node + 1];
  float b0 = 0.f, b1 = 0.f;
  for (int i = s + g; i < e; i += 2) {
    int c = cn[i];
    float2 v = up16(u_neg[(size_t)c * 32 + f]);
    b0 += v.x; b1 += v.y;
  }
  b0 += __shfl_xor(b0, 32);
  b1 += __shfl_xor(b1, 32);
  float invn = 1.f / (float)max(e - s, 1);

  if (g == 0) {
    size_t base = (size_t)node * 64 + 2 * f;
    float2 o;
    o.x = fmaxf(a0 * invp + b0 * invn + r2[base], 0.f);
    o.y = fmaxf(a1 * invp + b1 * invn + r2[base + 1], 0.f);
    *(float2*)(out + base) = o;
  }
}

// ---------------- launch ----------------

extern "C" void kernel_launch(void* const* d_in, const int* in_sizes, int n_in,
                              void* d_out, int out_size, void* d_ws, size_t ws_size,
                              hipStream_t stream) {
  const float* x     = (const float*)d_in[0];
  const int*   pe    = (const int*)d_in[1];
  const int*   ne    = (const int*)d_in[2];
  const float* w1_pl = (const float*)d_in[3];
  const float* w1_pr = (const float*)d_in[4];
  const float* b1_p  = (const float*)d_in[5];
  const float* w1_nl = (const float*)d_in[6];
  const float* w1_nr = (const float*)d_in[7];
  const float* b1_n  = (const float*)d_in[8];
  const float* w2_pl = (const float*)d_in[9];
  const float* w2_pr = (const float*)d_in[10];
  const float* b2_p  = (const float*)d_in[11];
  const float* w2_nl = (const float*)d_in[12];
  const float* w2_nr = (const float*)d_in[13];
  const float* b2_n  = (const float*)d_in[14];

  char* ws = (char*)d_ws;
  size_t off = 0;
  auto alloc = [&](size_t bytes) -> char* {
    char* p = ws + off;
    off = (off + bytes + 255) & ~(size_t)255;
    return p;
  };

  // deg halves contiguous: one exact memset covers both.
  int* deg   = (int*)alloc((size_t)2 * NN * 4);
  int* deg_p = deg;
  int* deg_n = deg + NN;
  int* row_p = (int*)alloc((size_t)(NN + 1) * 4);
  int* row_n = (int*)alloc((size_t)(NN + 1) * 4);
  int* col_p = (int*)alloc((size_t)NE * 4);
  int* col_n = (int*)alloc((size_t)NE * 4);
  int* bsum  = (int*)alloc((size_t)2 * 512 * 4);
  int* bofs  = (int*)alloc((size_t)2 * 512 * 4);

  // union region A (25.6MB): rank (k_rank..k_fill) / y1 (k_pre1..k_aggr1)
  //                        / u_pos+u_neg (k_mid..k_aggr2)
  char* regA   = alloc((size_t)NN * 64 * 4);
  int*  rank_p = (int*)regA;
  int*  rank_n = (int*)(regA + (size_t)NE * 4);
  uint* y1u    = (uint*)regA;
  uint* u_pos  = (uint*)regA;
  uint* u_neg  = (uint*)(regA + (size_t)NN * 32 * 4);

  float* r2 = (float*)alloc((size_t)NN * 64 * 4);

  // r1 and z both live in d_out; k_aggr2 fully overwrites d_out at the end.
  float* r1 = (float*)d_out;
  float* z  = (float*)d_out;

  hipMemsetAsync(deg, 0, (size_t)2 * NN * 4, stream);

  const int eb = (2 * NE + 255) / 256;
  const int nb = (NN + 255) / 256;
  const int ab = (NN * 64 + 255) / 256;

  k_rank<<<eb, 256, 0, stream>>>(pe, ne, deg_p, deg_n, rank_p, rank_n);

  dim3 sg(NBLK, 2);
  k_bsum<<<sg, 256, 0, stream>>>(deg, bsum);
  k_bscan<<<1, 1024, 0, stream>>>(bsum, bofs);
  k_rowwrite<<<sg, 256, 0, stream>>>(deg, bofs, row_p, row_n);

  k_fill<<<eb, 256, 0, stream>>>(pe, ne, row_p, row_n, rank_p, rank_n, col_p, col_n);

  dim3 g1(nb, 2);
  k_pre1<<<g1, 256, 0, stream>>>(x, w1_pl, w1_pr, b1_p, w1_nl, w1_nr, b1_n, y1u, r1);

  k_aggr1<<<ab, 256, 0, stream>>>(y1u, row_p, col_p, row_n, col_n, r1, z);

  dim3 g2(nb, 6);
  k_mid<<<g2, 256, 0, stream>>>(z, w2_pl, w2_pr, b2_p, w2_nl, w2_nr, b2_n,
                                u_pos, u_neg, r2);

  k_aggr2<<<ab, 256, 0, stream>>>(u_pos, u_neg, row_p, col_p, row_n, col_n, r2,
                                  (float*)d_out);
}

// Round 5
// 445.584 us; speedup vs baseline: 2.7047x; 1.2213x over previous
//
#include <hip/hip_runtime.h>
#include <hip/hip_fp16.h>

using uint = unsigned int;

static constexpr int NN  = 100000;   // nodes
static constexpr int NE  = 1600000;  // edges per set
static constexpr int DIM = 64;
static constexpr int HH  = 32;
static constexpr int NBLK = (NN + 255) / 256;       // 391 node-blocks
static constexpr int EB   = (2 * NE + 255) / 256;   // 12500 edge-blocks

__device__ __forceinline__ float2 up16(uint v) {
  __half2 h = *reinterpret_cast<__half2*>(&v);
  return __half22float2(h);
}
__device__ __forceinline__ uint pk16(float a, float b) {
  __half2 h = __floats2half2_rn(a, b);
  return *reinterpret_cast<uint*>(&h);
}

// ---------------- CSR build ----------------

// rank[e] = arrival order of edge e within its dst; deg[dst] counted as side effect.
__global__ void k_rank(const int* __restrict__ pe, const int* __restrict__ ne,
                       int* __restrict__ dp, int* __restrict__ dn,
                       int* __restrict__ rkp, int* __restrict__ rkn) {
  int t = blockIdx.x * 256 + threadIdx.x;
  if (t < NE) {
    rkp[t] = atomicAdd(&dp[pe[NE + t]], 1);
  } else if (t < 2 * NE) {
    int e = t - NE;
    rkn[e] = atomicAdd(&dn[ne[NE + e]], 1);
  }
}

// --- two-level scan: A) per-block sums, B) scan block sums, C) write rowptr ---

__global__ void k_bsum(const int* __restrict__ deg,  // [2*NN], set-major
                       int* __restrict__ bsum) {     // [2*512]
  int set = blockIdx.y;
  int i   = blockIdx.x * 256 + threadIdx.x;
  int v   = (i < NN) ? deg[set * NN + i] : 0;
  __shared__ int sm[256];
  sm[threadIdx.x] = v;
  __syncthreads();
  for (int off = 128; off > 0; off >>= 1) {
    if (threadIdx.x < off) sm[threadIdx.x] += sm[threadIdx.x + off];
    __syncthreads();
  }
  if (threadIdx.x == 0) bsum[set * 512 + blockIdx.x] = sm[0];
}

// One block, 1024 threads: independent exclusive scans of two 391-entry segments.
__global__ void k_bscan(const int* __restrict__ bsum, int* __restrict__ bofs) {
  int t   = threadIdx.x;
  int seg = t >> 9;        // 0 or 1
  int idx = t & 511;
  int v = (idx < NBLK) ? bsum[seg * 512 + idx] : 0;
  __shared__ int sm[1024];
  sm[t] = v;
  __syncthreads();
  for (int off = 1; off < 512; off <<= 1) {
    int add = (idx >= off) ? sm[t - off] : 0;
    __syncthreads();
    sm[t] += add;
    __syncthreads();
  }
  if (idx < NBLK) bofs[seg * 512 + idx] = (idx == 0) ? 0 : sm[t - 1];
}

__global__ void k_rowwrite(const int* __restrict__ deg,   // [2*NN]
                           const int* __restrict__ bofs,  // [2*512]
                           int* __restrict__ rp, int* __restrict__ rn) {
  int set = blockIdx.y;
  int* row = set ? rn : rp;
  int i = blockIdx.x * 256 + threadIdx.x;
  int v = (i < NN) ? deg[set * NN + i] : 0;
  __shared__ int sm[256];
  sm[threadIdx.x] = v;
  __syncthreads();
  for (int off = 1; off < 256; off <<= 1) {
    int add = (threadIdx.x >= off) ? sm[threadIdx.x - off] : 0;
    __syncthreads();
    sm[threadIdx.x] += add;
    __syncthreads();
  }
  int excl = (threadIdx.x == 0) ? 0 : sm[threadIdx.x - 1];
  if (i < NN) row[i] = bofs[set * 512 + blockIdx.x] + excl;
  if (blockIdx.x == NBLK - 1 && threadIdx.x == 255) row[NN] = NE;
}

// ---------------- fused fill + pre1 (independent work, one dispatch) ----------------
// Blocks [0, 2*NBLK): pre1   (y1 = x@wl in f16 -> regB; r1 = x@wr+b in f32 -> d_out)
// Blocks [2*NBLK, ..): fill  (col[row[dst]+rank[e]] = src; reads rank from regA)
// NOTE: y1 must NOT alias the rank buffers — pre1 and fill run concurrently here.
__global__ void k_fillpre(const int* __restrict__ pe, const int* __restrict__ ne,
                          const int* __restrict__ rp, const int* __restrict__ rn,
                          const int* __restrict__ rkp, const int* __restrict__ rkn,
                          int* __restrict__ cp, int* __restrict__ cn,
                          const float* __restrict__ x,
                          const float* __restrict__ w1_pl, const float* __restrict__ w1_pr,
                          const float* __restrict__ b1_p,
                          const float* __restrict__ w1_nl, const float* __restrict__ w1_nr,
                          const float* __restrict__ b1_n,
                          uint* __restrict__ y1u, float* __restrict__ r1) {
  if (blockIdx.x >= 2 * NBLK) {
    // ---- fill path ----
    int t = (blockIdx.x - 2 * NBLK) * 256 + threadIdx.x;
    if (t < NE) {
      int src = pe[t];
      int dst = pe[NE + t];
      cp[rp[dst] + rkp[t]] = src;
    } else if (t < 2 * NE) {
      int e = t - NE;
      int src = ne[e];
      int dst = ne[NE + e];
      cn[rn[dst] + rkn[e]] = src;
    }
    return;
  }

  // ---- pre1 path ----
  const int h    = (blockIdx.x >= NBLK) ? 1 : 0;
  const int nblk = blockIdx.x - (h ? NBLK : 0);
  const float* wl   = h ? w1_nl : w1_pl;  // [64][32]
  const float* wr   = h ? w1_nr : w1_pr;  // [64][32]
  const float* bias = h ? b1_n  : b1_p;

  __shared__ float s_wl[DIM][HH];
  __shared__ float s_wr[DIM][HH];
  for (int i = threadIdx.x; i < DIM * HH; i += 256) {
    s_wl[i >> 5][i & 31] = wl[i];
    s_wr[i >> 5][i & 31] = wr[i];
  }
  __syncthreads();

  int node = nblk * 256 + threadIdx.x;
  if (node >= NN) return;

  float ay[HH], ar[HH];
#pragma unroll
  for (int j = 0; j < HH; ++j) { ay[j] = 0.f; ar[j] = bias[j]; }

  const float4* xrow = (const float4*)(x + (size_t)node * DIM);
#pragma unroll 4
  for (int k4 = 0; k4 < DIM / 4; ++k4) {
    float4 xv = xrow[k4];
#pragma unroll
    for (int u = 0; u < 4; ++u) {
      int k = k4 * 4 + u;
      float xk = (&xv.x)[u];
#pragma unroll
      for (int j = 0; j < HH; ++j) {
        ay[j] += xk * s_wl[k][j];
        ar[j] += xk * s_wr[k][j];
      }
    }
  }

  uint*  yo = y1u + (size_t)node * 32 + h * 16;
  float* ro = r1  + (size_t)node * 64 + h * 32;
#pragma unroll
  for (int j = 0; j < 16; ++j) yo[j] = pk16(ay[2 * j], ay[2 * j + 1]);
#pragma unroll
  for (int j = 0; j < HH; ++j) ro[j] = ar[j];
}

// ---------------- aggregation 1 (wide gathers: 8 edges/iter, uint2 per lane) ---------
// y1 row = 32 uints: [pos half 0..15 | neg half 16..31]; lane = slot g (0..7) x fp f (0..7).
// Lane loads uint2 -> features 4f..4f+3 of the half. Butterfly xor 8/16/32 leaves the
// full sum in ALL lanes; g==0 writes pos half, g==1 writes neg half.
// NOTE: r1 and z ALIAS (both d_out): same-thread read-then-write only.
__global__ void k_aggr1(const uint* __restrict__ y1u,
                        const int* __restrict__ rp, const int* __restrict__ cp,
                        const int* __restrict__ rn, const int* __restrict__ cn,
                        const float* r1,
                        float* z) {
  int gid  = blockIdx.x * 256 + threadIdx.x;
  int node = gid >> 6;
  if (node >= NN) return;
  int lane = threadIdx.x & 63;
  int g = lane >> 3;      // edge slot 0..7
  int f = lane & 7;       // features 4f..4f+3 within a 32-half

  // pos
  int s = rp[node], e = rp[node + 1];
  float a0 = 0.f, a1 = 0.f, a2 = 0.f, a3 = 0.f;
  for (int i = s + g; i < e; i += 8) {
    int c = cp[i];
    uint2 v = *(const uint2*)&y1u[(size_t)c * 32 + 2 * f];
    float2 lo = up16(v.x), hi = up16(v.y);
    a0 += lo.x; a1 += lo.y; a2 += hi.x; a3 += hi.y;
  }
#pragma unroll
  for (int w = 8; w <= 32; w <<= 1) {
    a0 += __shfl_xor(a0, w); a1 += __shfl_xor(a1, w);
    a2 += __shfl_xor(a2, w); a3 += __shfl_xor(a3, w);
  }
  float invp = 1.f / (float)max(e - s, 1);

  // neg
  s = rn[node]; e = rn[node + 1];
  float b0 = 0.f, b1 = 0.f, b2 = 0.f, b3 = 0.f;
  for (int i = s + g; i < e; i += 8) {
    int c = cn[i];
    uint2 v = *(const uint2*)&y1u[(size_t)c * 32 + 16 + 2 * f];
    float2 lo = up16(v.x), hi = up16(v.y);
    b0 += lo.x; b1 += lo.y; b2 += hi.x; b3 += hi.y;
  }
#pragma unroll
  for (int w = 8; w <= 32; w <<= 1) {
    b0 += __shfl_xor(b0, w); b1 += __shfl_xor(b1, w);
    b2 += __shfl_xor(b2, w); b3 += __shfl_xor(b3, w);
  }
  float invn = 1.f / (float)max(e - s, 1);

  size_t base = (size_t)node * 64;
  if (g == 0) {
    const float4 r = *(const float4*)(r1 + base + 4 * f);
    float4 o;
    o.x = fmaxf(a0 * invp + r.x, 0.f);
    o.y = fmaxf(a1 * invp + r.y, 0.f);
    o.z = fmaxf(a2 * invp + r.z, 0.f);
    o.w = fmaxf(a3 * invp + r.w, 0.f);
    *(float4*)(z + base + 4 * f) = o;
  } else if (g == 1) {
    const float4 r = *(const float4*)(r1 + base + 32 + 4 * f);
    float4 o;
    o.x = fmaxf(b0 * invn + r.x, 0.f);
    o.y = fmaxf(b1 * invn + r.y, 0.f);
    o.z = fmaxf(b2 * invn + r.z, 0.f);
    o.w = fmaxf(b3 * invn + r.w, 0.f);
    *(float4*)(z + base + 32 + 4 * f) = o;
  }
}

// ---------------- pre-transform layer 2 ----------------
__global__ void k_mid(const float* __restrict__ z,
                      const float* __restrict__ w2_pl, const float* __restrict__ w2_pr,
                      const float* __restrict__ b2_p,
                      const float* __restrict__ w2_nl, const float* __restrict__ w2_nr,
                      const float* __restrict__ b2_n,
                      uint* __restrict__ u_pos, uint* __restrict__ u_neg,
                      float* __restrict__ r2) {
  const int t = blockIdx.y;
  const float* mat;
  const float* bias = nullptr;
  int srcHalf;            // 0 = zp, 1 = zn
  switch (t) {
    case 0: mat = w2_pl;            srcHalf = 0; break;
    case 1: mat = w2_nl;            srcHalf = 1; break;
    case 2: mat = w2_pl + 32 * 32;  srcHalf = 1; break;
    case 3: mat = w2_nl + 32 * 32;  srcHalf = 0; break;
    case 4: mat = w2_pr; bias = b2_p; srcHalf = 0; break;
    default: mat = w2_nr; bias = b2_n; srcHalf = 1; break;
  }

  __shared__ float s_m[HH][HH];
  for (int i = threadIdx.x; i < HH * HH; i += 256) s_m[i >> 5][i & 31] = mat[i];
  __syncthreads();

  int node = blockIdx.x * 256 + threadIdx.x;
  if (node >= NN) return;

  float acc[HH];
#pragma unroll
  for (int j = 0; j < HH; ++j) acc[j] = bias ? bias[j] : 0.f;

  const float4* zrow = (const float4*)(z + (size_t)node * 64 + srcHalf * 32);
#pragma unroll 4
  for (int k4 = 0; k4 < HH / 4; ++k4) {
    float4 v = zrow[k4];
#pragma unroll
    for (int u = 0; u < 4; ++u) {
      int k = k4 * 4 + u;
      float vv = (&v.x)[u];
#pragma unroll
      for (int j = 0; j < HH; ++j) acc[j] += vv * s_m[k][j];
    }
  }

  if (t < 4) {
    uint* o = (t < 2 ? u_pos : u_neg) + (size_t)node * 32 + (t & 1) * 16;
#pragma unroll
    for (int j = 0; j < 16; ++j) o[j] = pk16(acc[2 * j], acc[2 * j + 1]);
  } else {
    float* o = r2 + (size_t)node * 64 + (t - 4) * 32;
#pragma unroll
    for (int j = 0; j < HH; ++j) o[j] = acc[j];
  }
}

// ---------------- aggregation 2 (wide gathers: 4 edges/iter, uint2 per lane) --------
// u row = 32 uints (64 f16). lane = slot g (0..3) x f (0..15); lane loads uint2 ->
// features 4f..4f+3. Butterfly xor 16/32; g==0 lanes write float4 (full 64-f row).
__global__ void k_aggr2(const uint* __restrict__ u_pos, const uint* __restrict__ u_neg,
                        const int* __restrict__ rp, const int* __restrict__ cp,
                        const int* __restrict__ rn, const int* __restrict__ cn,
                        const float* __restrict__ r2,
                        float* __restrict__ out) {
  int gid  = blockIdx.x * 256 + threadIdx.x;
  int node = gid >> 6;
  if (node >= NN) return;
  int lane = threadIdx.x & 63;
  int g = lane >> 4;      // edge slot 0..3
  int f = lane & 15;      // features 4f..4f+3

  int s = rp[node], e = rp[node + 1];
  float a0 = 0.f, a1 = 0.f, a2 = 0.f, a3 = 0.f;
  for (int i = s + g; i < e; i += 4) {
    int c = cp[i];
    uint2 v = *(const uint2*)&u_pos[(size_t)c * 32 + 2 * f];
    float2 lo = up16(v.x), hi = up16(v.y);
    a0 += lo.x; a1 += lo.y; a2 += hi.x; a3 += hi.y;
  }
#pragma unroll
  for (int w = 16; w <= 32; w <<= 1) {
    a0 += __shfl_xor(a0, w); a1 += __shfl_xor(a1, w);
    a2 += __shfl_xor(a2, w); a3 += __shfl_xor(a3, w);
  }
  float invp = 1.f / (float)max(e - s, 1);

  s = rn[node]; e = rn[node + 1];
  float b0 = 0.f, b1 = 0.f, b2 = 0.f, b3 = 0.f;
  for (int i = s + g; i < e; i += 4) {
    int c = cn[i];
    uint2 v = *(const uint2*)&u_neg[(size_t)c * 32 + 2 * f];
    float2 lo = up16(v.x), hi = up16(v.y);
    b0 += lo.x; b1 += lo.y; b2 += hi.x; b3 += hi.y;
  }
#pragma unroll
  for (int w = 16; w <= 32; w <<= 1) {
    b0 += __shfl_xor(b0, w); b1 += __shfl_xor(b1, w);
    b2 += __shfl_xor(b2, w); b3 += __shfl_xor(b3, w);
  }
  float invn = 1.f / (float)max(e - s, 1);

  if (g == 0) {
    size_t base = (size_t)node * 64 + 4 * f;
    const float4 r = *(const float4*)(r2 + base);
    float4 o;
    o.x = fmaxf(a0 * invp + b0 * invn + r.x, 0.f);
    o.y = fmaxf(a1 * invp + b1 * invn + r.y, 0.f);
    o.z = fmaxf(a2 * invp + b2 * invn + r.z, 0.f);
    o.w = fmaxf(a3 * invp + b3 * invn + r.w, 0.f);
    *(float4*)(out + base) = o;
  }
}

// ---------------- launch ----------------

extern "C" void kernel_launch(void* const* d_in, const int* in_sizes, int n_in,
                              void* d_out, int out_size, void* d_ws, size_t ws_size,
                              hipStream_t stream) {
  const float* x     = (const float*)d_in[0];
  const int*   pe    = (const int*)d_in[1];
  const int*   ne    = (const int*)d_in[2];
  const float* w1_pl = (const float*)d_in[3];
  const float* w1_pr = (const float*)d_in[4];
  const float* b1_p  = (const float*)d_in[5];
  const float* w1_nl = (const float*)d_in[6];
  const float* w1_nr = (const float*)d_in[7];
  const float* b1_n  = (const float*)d_in[8];
  const float* w2_pl = (const float*)d_in[9];
  const float* w2_pr = (const float*)d_in[10];
  const float* b2_p  = (const float*)d_in[11];
  const float* w2_nl = (const float*)d_in[12];
  const float* w2_nr = (const float*)d_in[13];
  const float* b2_n  = (const float*)d_in[14];

  char* ws = (char*)d_ws;
  size_t off = 0;
  auto alloc = [&](size_t bytes) -> char* {
    char* p = ws + off;
    off = (off + bytes + 255) & ~(size_t)255;
    return p;
  };

  // deg halves contiguous: one exact memset covers both.
  int* deg   = (int*)alloc((size_t)2 * NN * 4);
  int* deg_p = deg;
  int* deg_n = deg + NN;
  int* row_p = (int*)alloc((size_t)(NN + 1) * 4);
  int* row_n = (int*)alloc((size_t)(NN + 1) * 4);
  int* col_p = (int*)alloc((size_t)NE * 4);
  int* col_n = (int*)alloc((size_t)NE * 4);
  int* bsum  = (int*)alloc((size_t)2 * 512 * 4);
  int* bofs  = (int*)alloc((size_t)2 * 512 * 4);

  // union region A (25.6MB): rank (k_rank..k_fillpre's fill part)
  //                        / u_pos+u_neg (k_mid..k_aggr2)
  char* regA   = alloc((size_t)NN * 64 * 4);
  int*  rank_p = (int*)regA;
  int*  rank_n = (int*)(regA + (size_t)NE * 4);
  uint* u_pos  = (uint*)regA;
  uint* u_neg  = (uint*)(regA + (size_t)NN * 32 * 4);

  // union region B (25.6MB): y1 (k_fillpre..k_aggr1) / r2 (k_mid..k_aggr2).
  // y1 must NOT live in regA: pre1 (writes y1) and fill (reads rank) share a dispatch.
  char*  regB = alloc((size_t)NN * 64 * 4);
  uint*  y1u  = (uint*)regB;
  float* r2   = (float*)regB;

  // r1 and z both live in d_out; k_aggr2 fully overwrites d_out at the end.
  float* r1 = (float*)d_out;
  float* z  = (float*)d_out;

  hipMemsetAsync(deg, 0, (size_t)2 * NN * 4, stream);

  const int nb = NBLK;
  const int ab = (NN * 64 + 255) / 256;

  k_rank<<<EB, 256, 0, stream>>>(pe, ne, deg_p, deg_n, rank_p, rank_n);

  dim3 sg(NBLK, 2);
  k_bsum<<<sg, 256, 0, stream>>>(deg, bsum);
  k_bscan<<<1, 1024, 0, stream>>>(bsum, bofs);
  k_rowwrite<<<sg, 256, 0, stream>>>(deg, bofs, row_p, row_n);

  k_fillpre<<<2 * NBLK + EB, 256, 0, stream>>>(
      pe, ne, row_p, row_n, rank_p, rank_n, col_p, col_n,
      x, w1_pl, w1_pr, b1_p, w1_nl, w1_nr, b1_n, y1u, r1);

  k_aggr1<<<ab, 256, 0, stream>>>(y1u, row_p, col_p, row_n, col_n, r1, z);

  dim3 g2(nb, 6);
  k_mid<<<g2, 256, 0, stream>>>(z, w2_pl, w2_pr, b2_p, w2_nl, w2_nr, b2_n,
                                u_pos, u_neg, r2);

  k_aggr2<<<ab, 256, 0, stream>>>(u_pos, u_neg, row_p, col_p, row_n, col_n, r2,
                                  (float*)d_out);
}

// Round 6
// 318.544 us; speedup vs baseline: 3.7834x; 1.3988x over previous
//
#include <hip/hip_runtime.h>
#include <hip/hip_fp16.h>

using uint = unsigned int;

static constexpr int NN  = 100000;   // nodes
static constexpr int NE  = 1600000;  // edges per set
static constexpr int DIM = 64;
static constexpr int HH  = 32;
static constexpr int NBLK = (NN + 255) / 256;   // 391 node-blocks
static constexpr int HB   = 256;                // partition blocks per edge set
static constexpr int CHUNK = NE / HB;           // 6250 edges per block (exact)
static constexpr int BSH  = 9;                  // bucket = dst >> 9 (512 nodes/bucket)
static constexpr int BSZ  = 512;
static constexpr int NBKT = (NN + BSZ - 1) / BSZ;  // 196 live buckets

__device__ __forceinline__ float2 up16(uint v) {
  __half2 h = *reinterpret_cast<__half2*>(&v);
  return __half22float2(h);
}
__device__ __forceinline__ uint pk16(float a, float b) {
  __half2 h = __floats2half2_rn(a, b);
  return *reinterpret_cast<uint*>(&h);
}

// ================= atomic-free CSR build (radix partition by dst>>9) =================

// A1: per-block 256-bucket histogram. part_hist[set][b][k]
__global__ void c_hist(const int* __restrict__ pe, const int* __restrict__ ne,
                       int* __restrict__ part_hist) {
  const int set = blockIdx.y;
  const int* dstA = (set ? ne : pe) + NE;
  __shared__ int h[256];
  h[threadIdx.x] = 0;
  __syncthreads();
  int lo = blockIdx.x * CHUNK;
  int hi = lo + CHUNK;
  for (int i = lo + threadIdx.x; i < hi; i += 256)
    atomicAdd(&h[dstA[i] >> BSH], 1);
  __syncthreads();
  part_hist[(set * HB + blockIdx.x) * 256 + threadIdx.x] = h[threadIdx.x];
}

// A2: for each (set,bucket k): exclusive scan over the HB block-partials (in place),
// total -> tot[set][k].
__global__ void c_colscan(int* __restrict__ part_hist, int* __restrict__ tot) {
  const int set = blockIdx.y;
  const int k   = blockIdx.x;
  const int t   = threadIdx.x;   // indexes block b
  int v = part_hist[(set * HB + t) * 256 + k];
  __shared__ int sm[256];
  sm[t] = v;
  __syncthreads();
  for (int off = 1; off < 256; off <<= 1) {
    int add = (t >= off) ? sm[t - off] : 0;
    __syncthreads();
    sm[t] += add;
    __syncthreads();
  }
  part_hist[(set * HB + t) * 256 + k] = (t == 0) ? 0 : sm[t - 1];
  if (t == 255) tot[set * 256 + k] = sm[255];
}

// A3: one block, 512 threads: exclusive scan of tot per set -> base[set][0..256]
__global__ void c_basescan(const int* __restrict__ tot, int* __restrict__ base) {
  const int t   = threadIdx.x;
  const int seg = t >> 8;      // set
  const int idx = t & 255;     // bucket
  int v = tot[seg * 256 + idx];
  __shared__ int sm[512];
  sm[t] = v;
  __syncthreads();
  for (int off = 1; off < 256; off <<= 1) {
    int add = (idx >= off) ? sm[t - off] : 0;
    __syncthreads();
    sm[t] += add;
    __syncthreads();
  }
  base[seg * 257 + idx] = (idx == 0) ? 0 : sm[t - 1];
  if (idx == 255) base[seg * 257 + 256] = sm[t];   // == NE
}

// A4: scatter (src,dst) pairs into bucket-partitioned order. LDS counters start at the
// block's reserved absolute offset per bucket -> no global atomics.
__global__ void c_scatter(const int* __restrict__ pe, const int* __restrict__ ne,
                          const int* __restrict__ part_hist, const int* __restrict__ base,
                          int2* __restrict__ partP, int2* __restrict__ partN) {
  const int set = blockIdx.y;
  const int* srcA = set ? ne : pe;
  const int* dstA = srcA + NE;
  int2* part = set ? partN : partP;
  __shared__ int off[256];
  off[threadIdx.x] = base[set * 257 + threadIdx.x] +
                     part_hist[(set * HB + blockIdx.x) * 256 + threadIdx.x];
  __syncthreads();
  int lo = blockIdx.x * CHUNK;
  int hi = lo + CHUNK;
  for (int i = lo + threadIdx.x; i < hi; i += 256) {
    int src = srcA[i];
    int dst = dstA[i];
    int pos = atomicAdd(&off[dst >> BSH], 1);
    part[pos] = make_int2(src, dst);
  }
}

// B: per-bucket CSR (count -> LDS scan -> rowptr + col scatter), all conflicts in LDS.
// Fused: blocks [2*NBKT, 2*NBKT+2*NBLK) run the layer-1 pre-transform (pre1).
__global__ void c_bucket(const int2* __restrict__ partP, const int2* __restrict__ partN,
                         const int* __restrict__ base,
                         int* __restrict__ row_p, int* __restrict__ row_n,
                         int* __restrict__ col_p, int* __restrict__ col_n,
                         const float* __restrict__ x,
                         const float* __restrict__ w1_pl, const float* __restrict__ w1_pr,
                         const float* __restrict__ b1_p,
                         const float* __restrict__ w1_nl, const float* __restrict__ w1_nr,
                         const float* __restrict__ b1_n,
                         uint* __restrict__ y1u, float* __restrict__ r1) {
  const int bx = blockIdx.x;
  const int t  = threadIdx.x;

  if (bx < 2 * NBKT) {
    // ---- bucket-CSR path ----
    const int set = bx / NBKT;
    const int k   = bx - set * NBKT;
    const int2* part = set ? partN : partP;
    int* row = set ? row_n : row_p;
    int* col = set ? col_n : col_p;
    const int lo = k * BSZ;
    const int hi = min(lo + BSZ, NN);
    const int s = base[set * 257 + k];
    const int e = base[set * 257 + k + 1];

    __shared__ int cnt[BSZ], rowl[BSZ], cnt2[BSZ];
    cnt[t] = 0; cnt[t + 256] = 0;
    cnt2[t] = 0; cnt2[t + 256] = 0;
    __syncthreads();
    for (int i = s + t; i < e; i += 256)
      atomicAdd(&cnt[part[i].y - lo], 1);
    __syncthreads();
    rowl[t] = cnt[t]; rowl[t + 256] = cnt[t + 256];
    __syncthreads();
    for (int off = 1; off < BSZ; off <<= 1) {
      int a0 = (t >= off) ? rowl[t - off] : 0;
      int a1 = (t + 256 >= off) ? rowl[t + 256 - off] : 0;
      __syncthreads();
      rowl[t] += a0; rowl[t + 256] += a1;
      __syncthreads();
    }
    // rowl = inclusive scan; exclusive(l) = l ? rowl[l-1] : 0
    if (lo + t < hi)        row[lo + t]        = s + (t ? rowl[t - 1] : 0);
    if (lo + t + 256 < hi)  row[lo + t + 256]  = s + rowl[t + 255];
    if (k == NBKT - 1 && t == 0) row[NN] = NE;
    for (int i = s + t; i < e; i += 256) {
      int2 p = part[i];
      int l = p.y - lo;
      int pos = s + (l ? rowl[l - 1] : 0) + atomicAdd(&cnt2[l], 1);
      col[pos] = p.x;
    }
    return;
  }

  // ---- pre1 path: y1 = x@wl (f16); r1 = x@wr + b (f32, in d_out) ----
  const int pb   = bx - 2 * NBKT;
  const int h    = (pb >= NBLK) ? 1 : 0;
  const int nblk = pb - (h ? NBLK : 0);
  const float* wl   = h ? w1_nl : w1_pl;  // [64][32]
  const float* wr   = h ? w1_nr : w1_pr;  // [64][32]
  const float* bias = h ? b1_n  : b1_p;

  __shared__ float s_wl[DIM][HH];
  __shared__ float s_wr[DIM][HH];
  for (int i = t; i < DIM * HH; i += 256) {
    s_wl[i >> 5][i & 31] = wl[i];
    s_wr[i >> 5][i & 31] = wr[i];
  }
  __syncthreads();

  int node = nblk * 256 + t;
  if (node >= NN) return;

  float ay[HH], ar[HH];
#pragma unroll
  for (int j = 0; j < HH; ++j) { ay[j] = 0.f; ar[j] = bias[j]; }

  const float4* xrow = (const float4*)(x + (size_t)node * DIM);
#pragma unroll 4
  for (int k4 = 0; k4 < DIM / 4; ++k4) {
    float4 xv = xrow[k4];
#pragma unroll
    for (int u = 0; u < 4; ++u) {
      int k = k4 * 4 + u;
      float xk = (&xv.x)[u];
#pragma unroll
      for (int j = 0; j < HH; ++j) {
        ay[j] += xk * s_wl[k][j];
        ar[j] += xk * s_wr[k][j];
      }
    }
  }

  uint*  yo = y1u + (size_t)node * 32 + h * 16;
  float* ro = r1  + (size_t)node * 64 + h * 32;
#pragma unroll
  for (int j = 0; j < 16; ++j) yo[j] = pk16(ay[2 * j], ay[2 * j + 1]);
#pragma unroll
  for (int j = 0; j < HH; ++j) ro[j] = ar[j];
}

// ---------------- aggregation 1 (8 edges/iter, uint2 per lane) ----------------
// NOTE: r1 and z ALIAS (both d_out): same-thread read-then-write only.
__global__ void k_aggr1(const uint* __restrict__ y1u,
                        const int* __restrict__ rp, const int* __restrict__ cp,
                        const int* __restrict__ rn, const int* __restrict__ cn,
                        const float* r1,
                        float* z) {
  int gid  = blockIdx.x * 256 + threadIdx.x;
  int node = gid >> 6;
  if (node >= NN) return;
  int lane = threadIdx.x & 63;
  int g = lane >> 3;      // edge slot 0..7
  int f = lane & 7;       // features 4f..4f+3 within a 32-half

  int s = rp[node], e = rp[node + 1];
  float a0 = 0.f, a1 = 0.f, a2 = 0.f, a3 = 0.f;
  for (int i = s + g; i < e; i += 8) {
    int c = cp[i];
    uint2 v = *(const uint2*)&y1u[(size_t)c * 32 + 2 * f];
    float2 lo = up16(v.x), hi = up16(v.y);
    a0 += lo.x; a1 += lo.y; a2 += hi.x; a3 += hi.y;
  }
#pragma unroll
  for (int w = 8; w <= 32; w <<= 1) {
    a0 += __shfl_xor(a0, w); a1 += __shfl_xor(a1, w);
    a2 += __shfl_xor(a2, w); a3 += __shfl_xor(a3, w);
  }
  float invp = 1.f / (float)max(e - s, 1);

  s = rn[node]; e = rn[node + 1];
  float b0 = 0.f, b1 = 0.f, b2 = 0.f, b3 = 0.f;
  for (int i = s + g; i < e; i += 8) {
    int c = cn[i];
    uint2 v = *(const uint2*)&y1u[(size_t)c * 32 + 16 + 2 * f];
    float2 lo = up16(v.x), hi = up16(v.y);
    b0 += lo.x; b1 += lo.y; b2 += hi.x; b3 += hi.y;
  }
#pragma unroll
  for (int w = 8; w <= 32; w <<= 1) {
    b0 += __shfl_xor(b0, w); b1 += __shfl_xor(b1, w);
    b2 += __shfl_xor(b2, w); b3 += __shfl_xor(b3, w);
  }
  float invn = 1.f / (float)max(e - s, 1);

  size_t base = (size_t)node * 64;
  if (g == 0) {
    const float4 r = *(const float4*)(r1 + base + 4 * f);
    float4 o;
    o.x = fmaxf(a0 * invp + r.x, 0.f);
    o.y = fmaxf(a1 * invp + r.y, 0.f);
    o.z = fmaxf(a2 * invp + r.z, 0.f);
    o.w = fmaxf(a3 * invp + r.w, 0.f);
    *(float4*)(z + base + 4 * f) = o;
  } else if (g == 1) {
    const float4 r = *(const float4*)(r1 + base + 32 + 4 * f);
    float4 o;
    o.x = fmaxf(b0 * invn + r.x, 0.f);
    o.y = fmaxf(b1 * invn + r.y, 0.f);
    o.z = fmaxf(b2 * invn + r.z, 0.f);
    o.w = fmaxf(b3 * invn + r.w, 0.f);
    *(float4*)(z + base + 32 + 4 * f) = o;
  }
}

// ---------------- pre-transform layer 2 ----------------
__global__ void k_mid(const float* __restrict__ z,
                      const float* __restrict__ w2_pl, const float* __restrict__ w2_pr,
                      const float* __restrict__ b2_p,
                      const float* __restrict__ w2_nl, const float* __restrict__ w2_nr,
                      const float* __restrict__ b2_n,
                      uint* __restrict__ u_pos, uint* __restrict__ u_neg,
                      float* __restrict__ r2) {
  const int t = blockIdx.y;
  const float* mat;
  const float* bias = nullptr;
  int srcHalf;            // 0 = zp, 1 = zn
  switch (t) {
    case 0: mat = w2_pl;            srcHalf = 0; break;
    case 1: mat = w2_nl;            srcHalf = 1; break;
    case 2: mat = w2_pl + 32 * 32;  srcHalf = 1; break;
    case 3: mat = w2_nl + 32 * 32;  srcHalf = 0; break;
    case 4: mat = w2_pr; bias = b2_p; srcHalf = 0; break;
    default: mat = w2_nr; bias = b2_n; srcHalf = 1; break;
  }

  __shared__ float s_m[HH][HH];
  for (int i = threadIdx.x; i < HH * HH; i += 256) s_m[i >> 5][i & 31] = mat[i];
  __syncthreads();

  int node = blockIdx.x * 256 + threadIdx.x;
  if (node >= NN) return;

  float acc[HH];
#pragma unroll
  for (int j = 0; j < HH; ++j) acc[j] = bias ? bias[j] : 0.f;

  const float4* zrow = (const float4*)(z + (size_t)node * 64 + srcHalf * 32);
#pragma unroll 4
  for (int k4 = 0; k4 < HH / 4; ++k4) {
    float4 v = zrow[k4];
#pragma unroll
    for (int u = 0; u < 4; ++u) {
      int k = k4 * 4 + u;
      float vv = (&v.x)[u];
#pragma unroll
      for (int j = 0; j < HH; ++j) acc[j] += vv * s_m[k][j];
    }
  }

  if (t < 4) {
    uint* o = (t < 2 ? u_pos : u_neg) + (size_t)node * 32 + (t & 1) * 16;
#pragma unroll
    for (int j = 0; j < 16; ++j) o[j] = pk16(acc[2 * j], acc[2 * j + 1]);
  } else {
    float* o = r2 + (size_t)node * 64 + (t - 4) * 32;
#pragma unroll
    for (int j = 0; j < HH; ++j) o[j] = acc[j];
  }
}

// ---------------- aggregation 2 (4 edges/iter, uint2 per lane) ----------------
__global__ void k_aggr2(const uint* __restrict__ u_pos, const uint* __restrict__ u_neg,
                        const int* __restrict__ rp, const int* __restrict__ cp,
                        const int* __restrict__ rn, const int* __restrict__ cn,
                        const float* __restrict__ r2,
                        float* __restrict__ out) {
  int gid  = blockIdx.x * 256 + threadIdx.x;
  int node = gid >> 6;
  if (node >= NN) return;
  int lane = threadIdx.x & 63;
  int g = lane >> 4;      // edge slot 0..3
  int f = lane & 15;      // features 4f..4f+3

  int s = rp[node], e = rp[node + 1];
  float a0 = 0.f, a1 = 0.f, a2 = 0.f, a3 = 0.f;
  for (int i = s + g; i < e; i += 4) {
    int c = cp[i];
    uint2 v = *(const uint2*)&u_pos[(size_t)c * 32 + 2 * f];
    float2 lo = up16(v.x), hi = up16(v.y);
    a0 += lo.x; a1 += lo.y; a2 += hi.x; a3 += hi.y;
  }
#pragma unroll
  for (int w = 16; w <= 32; w <<= 1) {
    a0 += __shfl_xor(a0, w); a1 += __shfl_xor(a1, w);
    a2 += __shfl_xor(a2, w); a3 += __shfl_xor(a3, w);
  }
  float invp = 1.f / (float)max(e - s, 1);

  s = rn[node]; e = rn[node + 1];
  float b0 = 0.f, b1 = 0.f, b2 = 0.f, b3 = 0.f;
  for (int i = s + g; i < e; i += 4) {
    int c = cn[i];
    uint2 v = *(const uint2*)&u_neg[(size_t)c * 32 + 2 * f];
    float2 lo = up16(v.x), hi = up16(v.y);
    b0 += lo.x; b1 += lo.y; b2 += hi.x; b3 += hi.y;
  }
#pragma unroll
  for (int w = 16; w <= 32; w <<= 1) {
    b0 += __shfl_xor(b0, w); b1 += __shfl_xor(b1, w);
    b2 += __shfl_xor(b2, w); b3 += __shfl_xor(b3, w);
  }
  float invn = 1.f / (float)max(e - s, 1);

  if (g == 0) {
    size_t base = (size_t)node * 64 + 4 * f;
    const float4 r = *(const float4*)(r2 + base);
    float4 o;
    o.x = fmaxf(a0 * invp + b0 * invn + r.x, 0.f);
    o.y = fmaxf(a1 * invp + b1 * invn + r.y, 0.f);
    o.z = fmaxf(a2 * invp + b2 * invn + r.z, 0.f);
    o.w = fmaxf(a3 * invp + b3 * invn + r.w, 0.f);
    *(float4*)(out + base) = o;
  }
}

// ---------------- launch ----------------

extern "C" void kernel_launch(void* const* d_in, const int* in_sizes, int n_in,
                              void* d_out, int out_size, void* d_ws, size_t ws_size,
                              hipStream_t stream) {
  const float* x     = (const float*)d_in[0];
  const int*   pe    = (const int*)d_in[1];
  const int*   ne    = (const int*)d_in[2];
  const float* w1_pl = (const float*)d_in[3];
  const float* w1_pr = (const float*)d_in[4];
  const float* b1_p  = (const float*)d_in[5];
  const float* w1_nl = (const float*)d_in[6];
  const float* w1_nr = (const float*)d_in[7];
  const float* b1_n  = (const float*)d_in[8];
  const float* w2_pl = (const float*)d_in[9];
  const float* w2_pr = (const float*)d_in[10];
  const float* b2_p  = (const float*)d_in[11];
  const float* w2_nl = (const float*)d_in[12];
  const float* w2_nr = (const float*)d_in[13];
  const float* b2_n  = (const float*)d_in[14];

  char* ws = (char*)d_ws;
  size_t off = 0;
  auto alloc = [&](size_t bytes) -> char* {
    char* p = ws + off;
    off = (off + bytes + 255) & ~(size_t)255;
    return p;
  };

  int* row_p = (int*)alloc((size_t)(NN + 1) * 4);
  int* row_n = (int*)alloc((size_t)(NN + 1) * 4);
  int* col_p = (int*)alloc((size_t)NE * 4);
  int* col_n = (int*)alloc((size_t)NE * 4);
  int* part_hist = (int*)alloc((size_t)2 * HB * 256 * 4);  // 512KB
  int* tot   = (int*)alloc((size_t)2 * 256 * 4);
  int* base  = (int*)alloc((size_t)2 * 257 * 4);

  // union region A (25.6MB): (src,dst) pair arrays (c_scatter..c_bucket)
  //                        / u_pos+u_neg (k_mid..k_aggr2)
  char* regA  = alloc((size_t)2 * NE * 8);   // == NN*64*4
  int2* partP = (int2*)regA;
  int2* partN = (int2*)(regA + (size_t)NE * 8);
  uint* u_pos = (uint*)regA;
  uint* u_neg = (uint*)(regA + (size_t)NN * 32 * 4);

  // union region B (25.6MB): y1 (c_bucket..k_aggr1) / r2 (k_mid..k_aggr2)
  char*  regB = alloc((size_t)NN * 64 * 4);
  uint*  y1u  = (uint*)regB;
  float* r2   = (float*)regB;

  // r1 and z both live in d_out; k_aggr2 fully overwrites d_out at the end.
  float* r1 = (float*)d_out;
  float* z  = (float*)d_out;

  const int nb = NBLK;
  const int ab = (NN * 64 + 255) / 256;

  dim3 hg(HB, 2);
  c_hist<<<hg, 256, 0, stream>>>(pe, ne, part_hist);
  dim3 cg(256, 2);
  c_colscan<<<cg, 256, 0, stream>>>(part_hist, tot);
  c_basescan<<<1, 512, 0, stream>>>(tot, base);
  c_scatter<<<hg, 256, 0, stream>>>(pe, ne, part_hist, base, partP, partN);
  c_bucket<<<2 * NBKT + 2 * NBLK, 256, 0, stream>>>(
      partP, partN, base, row_p, row_n, col_p, col_n,
      x, w1_pl, w1_pr, b1_p, w1_nl, w1_nr, b1_n, y1u, r1);

  k_aggr1<<<ab, 256, 0, stream>>>(y1u, row_p, col_p, row_n, col_n, r1, z);

  dim3 g2(nb, 6);
  k_mid<<<g2, 256, 0, stream>>>(z, w2_pl, w2_pr, b2_p, w2_nl, w2_nr, b2_n,
                                u_pos, u_neg, r2);

  k_aggr2<<<ab, 256, 0, stream>>>(u_pos, u_neg, row_p, col_p, row_n, col_n, r2,
                                  (float*)d_out);
}

// Round 7
// 287.349 us; speedup vs baseline: 4.1941x; 1.1086x over previous
//
#include <hip/hip_runtime.h>
#include <hip/hip_fp16.h>

using uint = unsigned int;

static constexpr int NN  = 100000;   // nodes
static constexpr int NE  = 1600000;  // edges per set
static constexpr int DIM = 64;
static constexpr int HH  = 32;
static constexpr int NBLK = (NN + 255) / 256;   // 391 node-blocks
static constexpr int HB   = 256;                // partition blocks per edge set
static constexpr int CHUNK = NE / HB;           // 6250 edges per block (exact)
static constexpr int BSH  = 9;                  // bucket = dst >> 9 (512 nodes/bucket)
static constexpr int BSZ  = 512;
static constexpr int NBKT = (NN + BSZ - 1) / BSZ;  // 196 live buckets

__device__ __forceinline__ float2 up16(uint v) {
  __half2 h = *reinterpret_cast<__half2*>(&v);
  return __half22float2(h);
}
__device__ __forceinline__ uint pk16(float a, float b) {
  __half2 h = __floats2half2_rn(a, b);
  return *reinterpret_cast<uint*>(&h);
}

// ================= atomic-free CSR build (radix partition by dst>>9) =================

// A1: per-block 256-bucket histogram. part_hist[set][b][k]
__global__ void c_hist(const int* __restrict__ pe, const int* __restrict__ ne,
                       int* __restrict__ part_hist) {
  const int set = blockIdx.y;
  const int* dstA = (set ? ne : pe) + NE;
  __shared__ int h[256];
  h[threadIdx.x] = 0;
  __syncthreads();
  int lo = blockIdx.x * CHUNK;
  int hi = lo + CHUNK;
  for (int i = lo + threadIdx.x; i < hi; i += 256)
    atomicAdd(&h[dstA[i] >> BSH], 1);
  __syncthreads();
  part_hist[(set * HB + blockIdx.x) * 256 + threadIdx.x] = h[threadIdx.x];
}

// A2: for each (set,bucket k): exclusive scan over the HB block-partials (in place),
// total -> tot[set][k].
__global__ void c_colscan(int* __restrict__ part_hist, int* __restrict__ tot) {
  const int set = blockIdx.y;
  const int k   = blockIdx.x;
  const int t   = threadIdx.x;   // indexes block b
  int v = part_hist[(set * HB + t) * 256 + k];
  __shared__ int sm[256];
  sm[t] = v;
  __syncthreads();
  for (int off = 1; off < 256; off <<= 1) {
    int add = (t >= off) ? sm[t - off] : 0;
    __syncthreads();
    sm[t] += add;
    __syncthreads();
  }
  part_hist[(set * HB + t) * 256 + k] = (t == 0) ? 0 : sm[t - 1];
  if (t == 255) tot[set * 256 + k] = sm[255];
}

// A3: one block, 512 threads: exclusive scan of tot per set -> base[set][0..256]
__global__ void c_basescan(const int* __restrict__ tot, int* __restrict__ base) {
  const int t   = threadIdx.x;
  const int seg = t >> 8;      // set
  const int idx = t & 255;     // bucket
  int v = tot[seg * 256 + idx];
  __shared__ int sm[512];
  sm[t] = v;
  __syncthreads();
  for (int off = 1; off < 256; off <<= 1) {
    int add = (idx >= off) ? sm[t - off] : 0;
    __syncthreads();
    sm[t] += add;
    __syncthreads();
  }
  base[seg * 257 + idx] = (idx == 0) ? 0 : sm[t - 1];
  if (idx == 255) base[seg * 257 + 256] = sm[t];   // == NE
}

// A4: scatter packed (src<<9 | dst&511) into bucket-partitioned order. LDS counters
// start at the block's reserved absolute offset per bucket -> no global atomics.
__global__ void c_scatter(const int* __restrict__ pe, const int* __restrict__ ne,
                          const int* __restrict__ part_hist, const int* __restrict__ base,
                          uint* __restrict__ partP, uint* __restrict__ partN) {
  const int set = blockIdx.y;
  const int* srcA = set ? ne : pe;
  const int* dstA = srcA + NE;
  uint* part = set ? partN : partP;
  __shared__ int off[256];
  off[threadIdx.x] = base[set * 257 + threadIdx.x] +
                     part_hist[(set * HB + blockIdx.x) * 256 + threadIdx.x];
  __syncthreads();
  int lo = blockIdx.x * CHUNK;
  int hi = lo + CHUNK;
  for (int i = lo + threadIdx.x; i < hi; i += 256) {
    int src = srcA[i];
    int dst = dstA[i];
    int pos = atomicAdd(&off[dst >> BSH], 1);
    part[pos] = ((uint)src << BSH) | (uint)(dst & (BSZ - 1));
  }
}

// B: per-bucket CSR (count -> LDS scan -> rowptr + col scatter), all conflicts in LDS.
// Fused: blocks [2*NBKT, 2*NBKT+2*NBLK) run the layer-1 pre-transform (pre1).
__global__ void c_bucket(const uint* __restrict__ partP, const uint* __restrict__ partN,
                         const int* __restrict__ base,
                         int* __restrict__ row_p, int* __restrict__ row_n,
                         int* __restrict__ col_p, int* __restrict__ col_n,
                         const float* __restrict__ x,
                         const float* __restrict__ w1_pl, const float* __restrict__ w1_pr,
                         const float* __restrict__ b1_p,
                         const float* __restrict__ w1_nl, const float* __restrict__ w1_nr,
                         const float* __restrict__ b1_n,
                         uint* __restrict__ y1u, float* __restrict__ r1) {
  const int bx = blockIdx.x;
  const int t  = threadIdx.x;

  if (bx < 2 * NBKT) {
    // ---- bucket-CSR path ----
    const int set = bx / NBKT;
    const int k   = bx - set * NBKT;
    const uint* part = set ? partN : partP;
    int* row = set ? row_n : row_p;
    int* col = set ? col_n : col_p;
    const int lo = k * BSZ;
    const int hi = min(lo + BSZ, NN);
    const int s = base[set * 257 + k];
    const int e = base[set * 257 + k + 1];

    __shared__ int cnt[BSZ], rowl[BSZ], cnt2[BSZ];
    cnt[t] = 0; cnt[t + 256] = 0;
    cnt2[t] = 0; cnt2[t + 256] = 0;
    __syncthreads();
    for (int i = s + t; i < e; i += 256)
      atomicAdd(&cnt[part[i] & (BSZ - 1)], 1);
    __syncthreads();
    rowl[t] = cnt[t]; rowl[t + 256] = cnt[t + 256];
    __syncthreads();
    for (int off = 1; off < BSZ; off <<= 1) {
      int a0 = (t >= off) ? rowl[t - off] : 0;
      int a1 = (t + 256 >= off) ? rowl[t + 256 - off] : 0;
      __syncthreads();
      rowl[t] += a0; rowl[t + 256] += a1;
      __syncthreads();
    }
    // rowl = inclusive scan; exclusive(l) = l ? rowl[l-1] : 0
    if (lo + t < hi)        row[lo + t]        = s + (t ? rowl[t - 1] : 0);
    if (lo + t + 256 < hi)  row[lo + t + 256]  = s + rowl[t + 255];
    if (k == NBKT - 1 && t == 0) row[NN] = NE;
    for (int i = s + t; i < e; i += 256) {
      uint p = part[i];
      int l = p & (BSZ - 1);
      int pos = s + (l ? rowl[l - 1] : 0) + atomicAdd(&cnt2[l], 1);
      col[pos] = (int)(p >> BSH);
    }
    return;
  }

  // ---- pre1 path: y1 = x@wl (f16); r1 = x@wr + b (f32, in d_out) ----
  const int pb   = bx - 2 * NBKT;
  const int h    = (pb >= NBLK) ? 1 : 0;
  const int nblk = pb - (h ? NBLK : 0);
  const float* wl   = h ? w1_nl : w1_pl;  // [64][32]
  const float* wr   = h ? w1_nr : w1_pr;  // [64][32]
  const float* bias = h ? b1_n  : b1_p;

  __shared__ float s_wl[DIM][HH];
  __shared__ float s_wr[DIM][HH];
  for (int i = t; i < DIM * HH; i += 256) {
    s_wl[i >> 5][i & 31] = wl[i];
    s_wr[i >> 5][i & 31] = wr[i];
  }
  __syncthreads();

  int node = nblk * 256 + t;
  if (node >= NN) return;

  float ay[HH], ar[HH];
#pragma unroll
  for (int j = 0; j < HH; ++j) { ay[j] = 0.f; ar[j] = bias[j]; }

  const float4* xrow = (const float4*)(x + (size_t)node * DIM);
#pragma unroll 4
  for (int k4 = 0; k4 < DIM / 4; ++k4) {
    float4 xv = xrow[k4];
#pragma unroll
    for (int u = 0; u < 4; ++u) {
      int k = k4 * 4 + u;
      float xk = (&xv.x)[u];
#pragma unroll
      for (int j = 0; j < HH; ++j) {
        ay[j] += xk * s_wl[k][j];
        ar[j] += xk * s_wr[k][j];
      }
    }
  }

  uint*  yo = y1u + (size_t)node * 32 + h * 16;
  float* ro = r1  + (size_t)node * 64 + h * 32;
#pragma unroll
  for (int j = 0; j < 16; ++j) yo[j] = pk16(ay[2 * j], ay[2 * j + 1]);
#pragma unroll
  for (int j = 0; j < HH; ++j) ro[j] = ar[j];
}

// ---------------- aggregation 1 (16 edges/iter, uint4 per lane) ----------------
// y1 row = 32 uints: [pos 0..15 | neg 16..31]. lane = (g,f): g=lane>>2 (0..15 edge
// slots), f=lane&3. Lane loads uint4 = features 8f..8f+7 of its half.
// Butterfly xor 4/8/16/32 sums over g; every lane then holds its 8 features' sums.
// NOTE: r1 and z ALIAS (both d_out): same-thread read-then-write only.
__global__ void k_aggr1(const uint* __restrict__ y1u,
                        const int* __restrict__ rp, const int* __restrict__ cp,
                        const int* __restrict__ rn, const int* __restrict__ cn,
                        const float* r1,
                        float* z) {
  int gid  = blockIdx.x * 256 + threadIdx.x;
  int node = gid >> 6;
  if (node >= NN) return;
  int lane = threadIdx.x & 63;
  int g = lane >> 2;      // edge slot 0..15
  int f = lane & 3;       // uint4 index within a 16-uint half

  int s = rp[node], e = rp[node + 1];
  float a[8];
#pragma unroll
  for (int j = 0; j < 8; ++j) a[j] = 0.f;
  for (int i = s + g; i < e; i += 16) {
    int c = cp[i];
    uint4 v = *(const uint4*)&y1u[(size_t)c * 32 + 4 * f];
    float2 p0 = up16(v.x), p1 = up16(v.y), p2 = up16(v.z), p3 = up16(v.w);
    a[0] += p0.x; a[1] += p0.y; a[2] += p1.x; a[3] += p1.y;
    a[4] += p2.x; a[5] += p2.y; a[6] += p3.x; a[7] += p3.y;
  }
#pragma unroll
  for (int w = 4; w <= 32; w <<= 1) {
#pragma unroll
    for (int j = 0; j < 8; ++j) a[j] += __shfl_xor(a[j], w);
  }
  float invp = 1.f / (float)max(e - s, 1);

  s = rn[node]; e = rn[node + 1];
  float b[8];
#pragma unroll
  for (int j = 0; j < 8; ++j) b[j] = 0.f;
  for (int i = s + g; i < e; i += 16) {
    int c = cn[i];
    uint4 v = *(const uint4*)&y1u[(size_t)c * 32 + 16 + 4 * f];
    float2 p0 = up16(v.x), p1 = up16(v.y), p2 = up16(v.z), p3 = up16(v.w);
    b[0] += p0.x; b[1] += p0.y; b[2] += p1.x; b[3] += p1.y;
    b[4] += p2.x; b[5] += p2.y; b[6] += p3.x; b[7] += p3.y;
  }
#pragma unroll
  for (int w = 4; w <= 32; w <<= 1) {
#pragma unroll
    for (int j = 0; j < 8; ++j) b[j] += __shfl_xor(b[j], w);
  }
  float invn = 1.f / (float)max(e - s, 1);

  size_t base = (size_t)node * 64;
  if (g == 0) {
    // pos features 8f..8f+7
    const float4 r0 = *(const float4*)(r1 + base + 8 * f);
    const float4 r1v = *(const float4*)(r1 + base + 8 * f + 4);
    float4 o0, o1;
    o0.x = fmaxf(a[0] * invp + r0.x, 0.f);
    o0.y = fmaxf(a[1] * invp + r0.y, 0.f);
    o0.z = fmaxf(a[2] * invp + r0.z, 0.f);
    o0.w = fmaxf(a[3] * invp + r0.w, 0.f);
    o1.x = fmaxf(a[4] * invp + r1v.x, 0.f);
    o1.y = fmaxf(a[5] * invp + r1v.y, 0.f);
    o1.z = fmaxf(a[6] * invp + r1v.z, 0.f);
    o1.w = fmaxf(a[7] * invp + r1v.w, 0.f);
    *(float4*)(z + base + 8 * f) = o0;
    *(float4*)(z + base + 8 * f + 4) = o1;
  } else if (g == 1) {
    // neg features 8f..8f+7
    const float4 r0 = *(const float4*)(r1 + base + 32 + 8 * f);
    const float4 r1v = *(const float4*)(r1 + base + 32 + 8 * f + 4);
    float4 o0, o1;
    o0.x = fmaxf(b[0] * invn + r0.x, 0.f);
    o0.y = fmaxf(b[1] * invn + r0.y, 0.f);
    o0.z = fmaxf(b[2] * invn + r0.z, 0.f);
    o0.w = fmaxf(b[3] * invn + r0.w, 0.f);
    o1.x = fmaxf(b[4] * invn + r1v.x, 0.f);
    o1.y = fmaxf(b[5] * invn + r1v.y, 0.f);
    o1.z = fmaxf(b[6] * invn + r1v.z, 0.f);
    o1.w = fmaxf(b[7] * invn + r1v.w, 0.f);
    *(float4*)(z + base + 32 + 8 * f) = o0;
    *(float4*)(z + base + 32 + 8 * f + 4) = o1;
  }
}

// ---------------- pre-transform layer 2 ----------------
__global__ void k_mid(const float* __restrict__ z,
                      const float* __restrict__ w2_pl, const float* __restrict__ w2_pr,
                      const float* __restrict__ b2_p,
                      const float* __restrict__ w2_nl, const float* __restrict__ w2_nr,
                      const float* __restrict__ b2_n,
                      uint* __restrict__ u_pos, uint* __restrict__ u_neg,
                      float* __restrict__ r2) {
  const int t = blockIdx.y;
  const float* mat;
  const float* bias = nullptr;
  int srcHalf;            // 0 = zp, 1 = zn
  switch (t) {
    case 0: mat = w2_pl;            srcHalf = 0; break;
    case 1: mat = w2_nl;            srcHalf = 1; break;
    case 2: mat = w2_pl + 32 * 32;  srcHalf = 1; break;
    case 3: mat = w2_nl + 32 * 32;  srcHalf = 0; break;
    case 4: mat = w2_pr; bias = b2_p; srcHalf = 0; break;
    default: mat = w2_nr; bias = b2_n; srcHalf = 1; break;
  }

  __shared__ float s_m[HH][HH];
  for (int i = threadIdx.x; i < HH * HH; i += 256) s_m[i >> 5][i & 31] = mat[i];
  __syncthreads();

  int node = blockIdx.x * 256 + threadIdx.x;
  if (node >= NN) return;

  float acc[HH];
#pragma unroll
  for (int j = 0; j < HH; ++j) acc[j] = bias ? bias[j] : 0.f;

  const float4* zrow = (const float4*)(z + (size_t)node * 64 + srcHalf * 32);
#pragma unroll 4
  for (int k4 = 0; k4 < HH / 4; ++k4) {
    float4 v = zrow[k4];
#pragma unroll
    for (int u = 0; u < 4; ++u) {
      int k = k4 * 4 + u;
      float vv = (&v.x)[u];
#pragma unroll
      for (int j = 0; j < HH; ++j) acc[j] += vv * s_m[k][j];
    }
  }

  if (t < 4) {
    uint* o = (t < 2 ? u_pos : u_neg) + (size_t)node * 32 + (t & 1) * 16;
#pragma unroll
    for (int j = 0; j < 16; ++j) o[j] = pk16(acc[2 * j], acc[2 * j + 1]);
  } else {
    float* o = r2 + (size_t)node * 64 + (t - 4) * 32;
#pragma unroll
    for (int j = 0; j < HH; ++j) o[j] = acc[j];
  }
}

// ---------------- aggregation 2 (8 edges/iter, uint4 per lane) ----------------
// u row = 32 uints (64 f16). lane = (g,f): g=lane>>3 (0..7 edge slots), f=lane&7.
// Lane loads uint4 = features 8f..8f+7. Butterfly xor 8/16/32 sums over g.
__global__ void k_aggr2(const uint* __restrict__ u_pos, const uint* __restrict__ u_neg,
                        const int* __restrict__ rp, const int* __restrict__ cp,
                        const int* __restrict__ rn, const int* __restrict__ cn,
                        const float* __restrict__ r2,
                        float* __restrict__ out) {
  int gid  = blockIdx.x * 256 + threadIdx.x;
  int node = gid >> 6;
  if (node >= NN) return;
  int lane = threadIdx.x & 63;
  int g = lane >> 3;      // edge slot 0..7
  int f = lane & 7;       // uint4 index in row

  int s = rp[node], e = rp[node + 1];
  float a[8];
#pragma unroll
  for (int j = 0; j < 8; ++j) a[j] = 0.f;
  for (int i = s + g; i < e; i += 8) {
    int c = cp[i];
    uint4 v = *(const uint4*)&u_pos[(size_t)c * 32 + 4 * f];
    float2 p0 = up16(v.x), p1 = up16(v.y), p2 = up16(v.z), p3 = up16(v.w);
    a[0] += p0.x; a[1] += p0.y; a[2] += p1.x; a[3] += p1.y;
    a[4] += p2.x; a[5] += p2.y; a[6] += p3.x; a[7] += p3.y;
  }
#pragma unroll
  for (int w = 8; w <= 32; w <<= 1) {
#pragma unroll
    for (int j = 0; j < 8; ++j) a[j] += __shfl_xor(a[j], w);
  }
  float invp = 1.f / (float)max(e - s, 1);

  s = rn[node]; e = rn[node + 1];
  float b[8];
#pragma unroll
  for (int j = 0; j < 8; ++j) b[j] = 0.f;
  for (int i = s + g; i < e; i += 8) {
    int c = cn[i];
    uint4 v = *(const uint4*)&u_neg[(size_t)c * 32 + 4 * f];
    float2 p0 = up16(v.x), p1 = up16(v.y), p2 = up16(v.z), p3 = up16(v.w);
    b[0] += p0.x; b[1] += p0.y; b[2] += p1.x; b[3] += p1.y;
    b[4] += p2.x; b[5] += p2.y; b[6] += p3.x; b[7] += p3.y;
  }
#pragma unroll
  for (int w = 8; w <= 32; w <<= 1) {
#pragma unroll
    for (int j = 0; j < 8; ++j) b[j] += __shfl_xor(b[j], w);
  }
  float invn = 1.f / (float)max(e - s, 1);

  if (g == 0) {
    size_t base = (size_t)node * 64 + 8 * f;
    const float4 r0 = *(const float4*)(r2 + base);
    const float4 r1v = *(const float4*)(r2 + base + 4);
    float4 o0, o1;
    o0.x = fmaxf(a[0] * invp + b[0] * invn + r0.x, 0.f);
    o0.y = fmaxf(a[1] * invp + b[1] * invn + r0.y, 0.f);
    o0.z = fmaxf(a[2] * invp + b[2] * invn + r0.z, 0.f);
    o0.w = fmaxf(a[3] * invp + b[3] * invn + r0.w, 0.f);
    o1.x = fmaxf(a[4] * invp + b[4] * invn + r1v.x, 0.f);
    o1.y = fmaxf(a[5] * invp + b[5] * invn + r1v.y, 0.f);
    o1.z = fmaxf(a[6] * invp + b[6] * invn + r1v.z, 0.f);
    o1.w = fmaxf(a[7] * invp + b[7] * invn + r1v.w, 0.f);
    *(float4*)(out + base) = o0;
    *(float4*)(out + base + 4) = o1;
  }
}

// ---------------- launch ----------------

extern "C" void kernel_launch(void* const* d_in, const int* in_sizes, int n_in,
                              void* d_out, int out_size, void* d_ws, size_t ws_size,
                              hipStream_t stream) {
  const float* x     = (const float*)d_in[0];
  const int*   pe    = (const int*)d_in[1];
  const int*   ne    = (const int*)d_in[2];
  const float* w1_pl = (const float*)d_in[3];
  const float* w1_pr = (const float*)d_in[4];
  const float* b1_p  = (const float*)d_in[5];
  const float* w1_nl = (const float*)d_in[6];
  const float* w1_nr = (const float*)d_in[7];
  const float* b1_n  = (const float*)d_in[8];
  const float* w2_pl = (const float*)d_in[9];
  const float* w2_pr = (const float*)d_in[10];
  const float* b2_p  = (const float*)d_in[11];
  const float* w2_nl = (const float*)d_in[12];
  const float* w2_nr = (const float*)d_in[13];
  const float* b2_n  = (const float*)d_in[14];

  char* ws = (char*)d_ws;
  size_t off = 0;
  auto alloc = [&](size_t bytes) -> char* {
    char* p = ws + off;
    off = (off + bytes + 255) & ~(size_t)255;
    return p;
  };

  int* row_p = (int*)alloc((size_t)(NN + 1) * 4);
  int* row_n = (int*)alloc((size_t)(NN + 1) * 4);
  int* col_p = (int*)alloc((size_t)NE * 4);
  int* col_n = (int*)alloc((size_t)NE * 4);
  int* part_hist = (int*)alloc((size_t)2 * HB * 256 * 4);  // 512KB
  int* tot   = (int*)alloc((size_t)2 * 256 * 4);
  int* base  = (int*)alloc((size_t)2 * 257 * 4);

  // union region A (25.6MB): packed partition arrays (c_scatter..c_bucket, 12.8MB)
  //                        / u_pos+u_neg (k_mid..k_aggr2, 25.6MB)
  char* regA  = alloc((size_t)NN * 64 * 4);
  uint* partP = (uint*)regA;
  uint* partN = (uint*)(regA + (size_t)NE * 4);
  uint* u_pos = (uint*)regA;
  uint* u_neg = (uint*)(regA + (size_t)NN * 32 * 4);

  // union region B (25.6MB): y1 (c_bucket..k_aggr1) / r2 (k_mid..k_aggr2)
  char*  regB = alloc((size_t)NN * 64 * 4);
  uint*  y1u  = (uint*)regB;
  float* r2   = (float*)regB;

  // r1 and z both live in d_out; k_aggr2 fully overwrites d_out at the end.
  float* r1 = (float*)d_out;
  float* z  = (float*)d_out;

  const int nb = NBLK;
  const int ab = (NN * 64 + 255) / 256;

  dim3 hg(HB, 2);
  c_hist<<<hg, 256, 0, stream>>>(pe, ne, part_hist);
  dim3 cg(256, 2);
  c_colscan<<<cg, 256, 0, stream>>>(part_hist, tot);
  c_basescan<<<1, 512, 0, stream>>>(tot, base);
  c_scatter<<<hg, 256, 0, stream>>>(pe, ne, part_hist, base, partP, partN);
  c_bucket<<<2 * NBKT + 2 * NBLK, 256, 0, stream>>>(
      partP, partN, base, row_p, row_n, col_p, col_n,
      x, w1_pl, w1_pr, b1_p, w1_nl, w1_nr, b1_n, y1u, r1);

  k_aggr1<<<ab, 256, 0, stream>>>(y1u, row_p, col_p, row_n, col_n, r1, z);

  dim3 g2(nb, 6);
  k_mid<<<g2, 256, 0, stream>>>(z, w2_pl, w2_pr, b2_p, w2_nl, w2_nr, b2_n,
                                u_pos, u_neg, r2);

  k_aggr2<<<ab, 256, 0, stream>>>(u_pos, u_neg, row_p, col_p, row_n, col_n, r2,
                                  (float*)d_out);
}